// Round 1
// baseline (4369.170 us; speedup 1.0000x reference)
//
#include <hip/hip_runtime.h>
#include <math.h>

// Problem constants
#define D_    1024
#define H_    16
#define DH_   64
#define DC_   256
#define HID_  2048
#define E_    8
#define B_    2
#define T_    2048
#define S_    4096   // B*T tokens
#define EPS_  1e-6f

// ---------------------------------------------------------------------------
// Generic fp32 SGEMM: C(M,N) = A(M,K) @ B(K,N), row-major, M%128==0, N%128==0,
// K%8==0. 128x128 block tile, BK=8, 256 threads, 8x8 microtile with split
// columns (tx*4 and 64+tx*4) to keep LDS B-reads 2-way-conflict-free.
// ---------------------------------------------------------------------------
__global__ __launch_bounds__(256) void sgemm_nn(const float* __restrict__ A,
                                                const float* __restrict__ B,
                                                float* __restrict__ C,
                                                int M, int N, int K) {
    __shared__ float As[8][132];
    __shared__ float Bs[8][132];
    const int tid  = threadIdx.x;
    const int row0 = blockIdx.y * 128;
    const int col0 = blockIdx.x * 128;
    const int arow = tid >> 1;
    const int acol = (tid & 1) << 2;
    const int brow = tid >> 5;
    const int bcol = (tid & 31) << 2;
    const int ty   = tid >> 4;
    const int tx   = tid & 15;
    float acc[8][8];
#pragma unroll
    for (int i = 0; i < 8; i++)
#pragma unroll
        for (int j = 0; j < 8; j++) acc[i][j] = 0.f;

    const float* Aptr = A + (size_t)(row0 + arow) * K + acol;
    const float* Bptr = B + (size_t)brow * N + col0 + bcol;

    for (int k0 = 0; k0 < K; k0 += 8) {
        float4 av = *(const float4*)(Aptr + k0);
        float4 bv = *(const float4*)(Bptr + (size_t)k0 * N);
        __syncthreads();
        As[acol + 0][arow] = av.x;
        As[acol + 1][arow] = av.y;
        As[acol + 2][arow] = av.z;
        As[acol + 3][arow] = av.w;
        *(float4*)(&Bs[brow][bcol]) = bv;
        __syncthreads();
#pragma unroll
        for (int kk = 0; kk < 8; kk++) {
            float a[8], b[8];
            *(float4*)(a)     = *(const float4*)(&As[kk][ty * 8]);
            *(float4*)(a + 4) = *(const float4*)(&As[kk][ty * 8 + 4]);
            *(float4*)(b)     = *(const float4*)(&Bs[kk][tx * 4]);
            *(float4*)(b + 4) = *(const float4*)(&Bs[kk][64 + tx * 4]);
#pragma unroll
            for (int i = 0; i < 8; i++)
#pragma unroll
                for (int j = 0; j < 8; j++) acc[i][j] += a[i] * b[j];
        }
    }
#pragma unroll
    for (int i = 0; i < 8; i++) {
        float* crow = C + (size_t)(row0 + ty * 8 + i) * N + col0;
        float4 c0 = {acc[i][0], acc[i][1], acc[i][2], acc[i][3]};
        float4 c1 = {acc[i][4], acc[i][5], acc[i][6], acc[i][7]};
        *(float4*)(crow + tx * 4)      = c0;
        *(float4*)(crow + 64 + tx * 4) = c1;
    }
}

// ---------------------------------------------------------------------------
// Routed-expert GEMM: gathered A rows (token list), B = W2_experts[e],
// scaled by per-token routing weight, atomicAdd into C (on top of shared FFN).
// grid: x = D_/128 n-tiles, y = expert*32 + m-tile (max 32 tiles = 4096 rows).
// ---------------------------------------------------------------------------
__global__ __launch_bounds__(256) void routed_gemm(const float* __restrict__ Hh,
                                                   const float* __restrict__ W2,
                                                   const int* __restrict__ list,
                                                   const float* __restrict__ wlist,
                                                   const int* __restrict__ bases,
                                                   const int* __restrict__ counts,
                                                   float* __restrict__ Cout) {
    const int e    = blockIdx.y >> 5;
    const int tile = blockIdx.y & 31;
    const int cnt  = counts[e];
    if (tile * 128 >= cnt) return;
    const int base = bases[e];

    __shared__ int   toks[128];
    __shared__ float wrow[128];
    __shared__ float As[8][132];
    __shared__ float Bs[8][132];

    const int tid = threadIdx.x;
    if (tid < 128) {
        int ridx = tile * 128 + tid;
        if (ridx < cnt) {
            toks[tid] = list[base + ridx];
            wrow[tid] = wlist[base + ridx];
        } else {
            toks[tid] = -1;
            wrow[tid] = 0.f;
        }
    }
    __syncthreads();

    const int col0 = blockIdx.x * 128;
    const int arow = tid >> 1;
    const int acol = (tid & 1) << 2;
    const int brow = tid >> 5;
    const int bcol = (tid & 31) << 2;
    const int ty   = tid >> 4;
    const int tx   = tid & 15;

    const int atok = toks[arow];
    const float* Aptr  = Hh + (size_t)(atok < 0 ? 0 : atok) * HID_ + acol;
    const bool   avalid = (atok >= 0);
    const float* Bbase = W2 + (size_t)e * HID_ * D_ + col0 + bcol;

    float acc[8][8];
#pragma unroll
    for (int i = 0; i < 8; i++)
#pragma unroll
        for (int j = 0; j < 8; j++) acc[i][j] = 0.f;

    for (int k0 = 0; k0 < HID_; k0 += 8) {
        float4 av = make_float4(0.f, 0.f, 0.f, 0.f);
        if (avalid) av = *(const float4*)(Aptr + k0);
        float4 bv = *(const float4*)(Bbase + (size_t)(k0 + brow) * D_);
        __syncthreads();
        As[acol + 0][arow] = av.x;
        As[acol + 1][arow] = av.y;
        As[acol + 2][arow] = av.z;
        As[acol + 3][arow] = av.w;
        *(float4*)(&Bs[brow][bcol]) = bv;
        __syncthreads();
#pragma unroll
        for (int kk = 0; kk < 8; kk++) {
            float a[8], b[8];
            *(float4*)(a)     = *(const float4*)(&As[kk][ty * 8]);
            *(float4*)(a + 4) = *(const float4*)(&As[kk][ty * 8 + 4]);
            *(float4*)(b)     = *(const float4*)(&Bs[kk][tx * 4]);
            *(float4*)(b + 4) = *(const float4*)(&Bs[kk][64 + tx * 4]);
#pragma unroll
            for (int i = 0; i < 8; i++)
#pragma unroll
                for (int j = 0; j < 8; j++) acc[i][j] += a[i] * b[j];
        }
    }
#pragma unroll
    for (int i = 0; i < 8; i++) {
        int tk = toks[ty * 8 + i];
        if (tk < 0) continue;
        float wv = wrow[ty * 8 + i];
        float* crow = Cout + (size_t)tk * D_ + col0;
#pragma unroll
        for (int j = 0; j < 4; j++) atomicAdd(crow + tx * 4 + j, acc[i][j] * wv);
#pragma unroll
        for (int j = 0; j < 4; j++) atomicAdd(crow + 64 + tx * 4 + j, acc[i][4 + j] * wv);
    }
}

// ---------------------------------------------------------------------------
// RoPE, in place on a (S_, D_) buffer laid out [token][head*64 + d].
// position = token % T_; pair index i within head; interleaved rotate.
// ---------------------------------------------------------------------------
__global__ __launch_bounds__(256) void rope_kernel(float* __restrict__ x) {
    size_t p = (size_t)blockIdx.x * 256 + threadIdx.x;  // pair id, S_*D_/2 total
    int s = (int)(p / (D_ / 2));
    int r = (int)(p % (D_ / 2));
    int t = s & (T_ - 1);
    int d = r * 2;
    int i = (d & (DH_ - 1)) >> 1;            // 0..31
    float ang = (float)t * powf(10000.f, -(float)i / 32.f);
    float sn, cs;
    sincosf(ang, &sn, &cs);
    float* px = x + (size_t)s * D_ + d;
    float x1 = px[0], x2 = px[1];
    px[0] = x1 * cs - x2 * sn;
    px[1] = x1 * sn + x2 * cs;
}

// ---------------------------------------------------------------------------
// Flash-style attention. grid (T_/64, B_*H_), 256 threads.
// Thread (r = tid>>2, g = tid&3) owns q-row r, d-slice [g*16, g*16+16).
// Scores via 4-lane shuffle reduction; online softmax; V from LDS.
// ---------------------------------------------------------------------------
__global__ __launch_bounds__(256) void attn_kernel(const float* __restrict__ q,
                                                   const float* __restrict__ k,
                                                   const float* __restrict__ v,
                                                   float* __restrict__ o) {
    __shared__ float Ks[64][68];
    __shared__ float Vs[64][68];
    const int tid = threadIdx.x;
    const int r = tid >> 2;
    const int g = tid & 3;
    const int bh = blockIdx.y;
    const int b = bh >> 4;
    const int h = bh & 15;
    const int qrow = b * T_ + blockIdx.x * 64 + r;
    const float* qp = q + (size_t)qrow * D_ + h * DH_ + g * 16;

    float Q[16], O[16];
#pragma unroll
    for (int i = 0; i < 16; i += 4) {
        float4 t4 = *(const float4*)(qp + i);
        Q[i] = t4.x; Q[i + 1] = t4.y; Q[i + 2] = t4.z; Q[i + 3] = t4.w;
    }
#pragma unroll
    for (int i = 0; i < 16; i++) O[i] = 0.f;
    float mval = -INFINITY, l = 0.f;

    for (int kt = 0; kt < T_ / 64; kt++) {
        const int krow = b * T_ + kt * 64 + r;
        const float* kp = k + (size_t)krow * D_ + h * DH_ + g * 16;
        const float* vp = v + (size_t)krow * D_ + h * DH_ + g * 16;
        __syncthreads();
#pragma unroll
        for (int i = 0; i < 16; i += 4) {
            *(float4*)(&Ks[r][g * 16 + i]) = *(const float4*)(kp + i);
            *(float4*)(&Vs[r][g * 16 + i]) = *(const float4*)(vp + i);
        }
        __syncthreads();

        float sc[64];
#pragma unroll
        for (int c = 0; c < 64; c++) {
            float p = 0.f;
#pragma unroll
            for (int i = 0; i < 16; i++) p += Q[i] * Ks[c][g * 16 + i];
            p += __shfl_xor(p, 1);
            p += __shfl_xor(p, 2);
            sc[c] = p * 0.125f;   // 1/sqrt(64)
        }
        float tmax = mval;
#pragma unroll
        for (int c = 0; c < 64; c++) tmax = fmaxf(tmax, sc[c]);
        float alpha = (mval == -INFINITY) ? 0.f : expf(mval - tmax);
        mval = tmax;
        float psum = 0.f;
#pragma unroll
        for (int c = 0; c < 64; c++) {
            float e2 = expf(sc[c] - mval);
            sc[c] = e2;
            psum += e2;
        }
        l = l * alpha + psum;
#pragma unroll
        for (int i = 0; i < 16; i++) O[i] *= alpha;
#pragma unroll
        for (int c = 0; c < 64; c++) {
#pragma unroll
            for (int i = 0; i < 16; i++) O[i] += sc[c] * Vs[c][g * 16 + i];
        }
    }
    float inv = 1.f / l;
    float* op = o + (size_t)qrow * D_ + h * DH_ + g * 16;
#pragma unroll
    for (int i = 0; i < 16; i += 4) {
        float4 t4 = {O[i] * inv, O[i + 1] * inv, O[i + 2] * inv, O[i + 3] * inv};
        *(float4*)(op + i) = t4;
    }
}

// ---------------------------------------------------------------------------
// Residual add + RMSNorm: out[s] = (a[s]+b[s]) * rsqrt(mean((a+b)^2)+eps) * w
// ---------------------------------------------------------------------------
__global__ __launch_bounds__(256) void rmsnorm_res(const float* __restrict__ a,
                                                   const float* __restrict__ b,
                                                   const float* __restrict__ w,
                                                   float* __restrict__ out) {
    const int s = blockIdx.x;
    const float* ar = a + (size_t)s * D_;
    const float* br = b + (size_t)s * D_;
    float y[4];
    float ss = 0.f;
#pragma unroll
    for (int kx = 0; kx < 4; kx++) {
        int j = threadIdx.x + kx * 256;
        y[kx] = ar[j] + br[j];
        ss += y[kx] * y[kx];
    }
    __shared__ float red[4];
#pragma unroll
    for (int off = 32; off > 0; off >>= 1) ss += __shfl_down(ss, off);
    int lane = threadIdx.x & 63, wv = threadIdx.x >> 6;
    if (lane == 0) red[wv] = ss;
    __syncthreads();
    float tot = red[0] + red[1] + red[2] + red[3];
    float scale = rsqrtf(tot / (float)D_ + EPS_);
    float* orow = out + (size_t)s * D_;
#pragma unroll
    for (int kx = 0; kx < 4; kx++) {
        int j = threadIdx.x + kx * 256;
        orow[j] = y[kx] * scale * w[j];
    }
}

// ---------------------------------------------------------------------------
// SwiGLU: h[s][j] = silu(mid[s][j]) * mid[s][HID_+j], mid rows are 2*HID_.
// ---------------------------------------------------------------------------
__global__ __launch_bounds__(256) void swiglu_kernel(const float* __restrict__ mid,
                                                     float* __restrict__ h) {
    size_t idx = (size_t)blockIdx.x * 256 + threadIdx.x;  // S_*HID_ total
    size_t srow = idx / HID_;
    int j = (int)(idx % HID_);
    float a  = mid[srow * (2 * HID_) + j];
    float bb = mid[srow * (2 * HID_) + HID_ + j];
    float sig = 1.f / (1.f + expf(-a));
    h[idx] = a * sig * bb;
}

// ---------------------------------------------------------------------------
// Gating: one wave per token. Computes group softmax/argmax, in-group expert
// softmax, top-2, writes per-token (expert id, weight) and bumps counts.
// ---------------------------------------------------------------------------
__global__ __launch_bounds__(256) void gate_kernel(const float* __restrict__ x,
                                                   const float* __restrict__ Wg,
                                                   const float* __restrict__ We,
                                                   const float* __restrict__ gb,
                                                   const float* __restrict__ eb,
                                                   int* __restrict__ tok_e,
                                                   float* __restrict__ tok_w,
                                                   int* __restrict__ counts) {
    const int wave = threadIdx.x >> 6;
    const int lane = threadIdx.x & 63;
    const int s = blockIdx.x * 4 + wave;
    const float* xr = x + (size_t)s * D_;
    float g0 = 0.f, g1 = 0.f;
    float ee[8];
#pragma unroll
    for (int e = 0; e < 8; e++) ee[e] = 0.f;
    for (int j = lane; j < D_; j += 64) {
        float xv = xr[j];
        g0 += xv * Wg[j * 2 + 0];
        g1 += xv * Wg[j * 2 + 1];
#pragma unroll
        for (int e = 0; e < 8; e++) ee[e] += xv * We[j * 8 + e];
    }
#pragma unroll
    for (int off = 32; off > 0; off >>= 1) {
        g0 += __shfl_down(g0, off);
        g1 += __shfl_down(g1, off);
#pragma unroll
        for (int e = 0; e < 8; e++) ee[e] += __shfl_down(ee[e], off);
    }
    if (lane == 0) {
        g0 += gb[0];
        g1 += gb[1];
        int gidx = (g1 > g0) ? 1 : 0;
        float gm = fmaxf(g0, g1);
        float p0 = expf(g0 - gm), p1 = expf(g1 - gm);
        float gprob = (gidx ? p1 : p0) / (p0 + p1);
        int base = gidx * 4;
        float pe[4];
        float em = -INFINITY;
#pragma unroll
        for (int i = 0; i < 4; i++) {
            pe[i] = ee[base + i] + eb[base + i];
            em = fmaxf(em, pe[i]);
        }
        float sum = 0.f;
#pragma unroll
        for (int i = 0; i < 4; i++) {
            pe[i] = expf(pe[i] - em);
            sum += pe[i];
        }
        float inv = gprob / sum;
#pragma unroll
        for (int i = 0; i < 4; i++) pe[i] *= inv;
        // top-2, first-occurrence tie-breaking (matches jax.lax.top_k)
        int i1 = 0;
        for (int i = 1; i < 4; i++)
            if (pe[i] > pe[i1]) i1 = i;
        int i2 = -1;
        for (int i = 0; i < 4; i++) {
            if (i == i1) continue;
            if (i2 < 0 || pe[i] > pe[i2]) i2 = i;
        }
        tok_e[s * 2 + 0] = base + i1;
        tok_e[s * 2 + 1] = base + i2;
        tok_w[s * 2 + 0] = pe[i1];
        tok_w[s * 2 + 1] = pe[i2];
        atomicAdd(&counts[base + i1], 1);
        atomicAdd(&counts[base + i2], 1);
    }
}

__global__ void zero_counts(int* counts) {
    if (threadIdx.x < E_) counts[threadIdx.x] = 0;
}

__global__ void scan_kernel(const int* __restrict__ counts,
                            int* __restrict__ bases,
                            int* __restrict__ cursors) {
    if (threadIdx.x == 0 && blockIdx.x == 0) {
        int acc = 0;
        for (int e = 0; e < E_; e++) {
            bases[e] = acc;
            cursors[e] = acc;
            acc += counts[e];
        }
    }
}

__global__ __launch_bounds__(256) void scatter_kernel(const int* __restrict__ tok_e,
                                                      const float* __restrict__ tok_w,
                                                      int* __restrict__ cursors,
                                                      int* __restrict__ list,
                                                      float* __restrict__ wlist) {
    int s = blockIdx.x * 256 + threadIdx.x;
    if (s >= S_) return;
#pragma unroll
    for (int t = 0; t < 2; t++) {
        int e = tok_e[s * 2 + t];
        int pos = atomicAdd(&cursors[e], 1);
        list[pos] = s;
        wlist[pos] = tok_w[s * 2 + t];
    }
}

// ---------------------------------------------------------------------------
extern "C" void kernel_launch(void* const* d_in, const int* in_sizes, int n_in,
                              void* d_out, int out_size, void* d_ws, size_t ws_size,
                              hipStream_t stream) {
    const float* src  = (const float*)d_in[0];
    const float* Wq   = (const float*)d_in[1];
    const float* Wk_c = (const float*)d_in[2];
    const float* Wv_c = (const float*)d_in[3];
    const float* Wk   = (const float*)d_in[4];
    const float* Wv   = (const float*)d_in[5];
    const float* Wo   = (const float*)d_in[6];
    const float* Wsin = (const float*)d_in[7];
    const float* Wsout= (const float*)d_in[8];
    const float* W1   = (const float*)d_in[9];
    const float* W2   = (const float*)d_in[10];
    const float* Wg   = (const float*)d_in[11];
    const float* We   = (const float*)d_in[12];
    const float* gb   = (const float*)d_in[13];
    const float* eb   = (const float*)d_in[14];
    const float* n1w  = (const float*)d_in[15];
    const float* n2w  = (const float*)d_in[16];
    float* out = (float*)d_out;

    float* ws = (float*)d_ws;
    // layout: [q k v kc vc sa | x1 | ffn | hbuf | small]; mid overlays q..sa
    float* q   = ws;
    float* k   = q  + (size_t)S_ * D_;
    float* v   = k  + (size_t)S_ * D_;
    float* kc  = v  + (size_t)S_ * D_;
    float* vc  = kc + (size_t)S_ * DC_;
    float* sa  = vc + (size_t)S_ * DC_;
    float* mid = ws;                                  // overlays q..sa (needs S_*2*HID_ = 16.78M < 18.87M)
    float* x1  = sa + (size_t)S_ * D_;
    float* ffn = x1 + (size_t)S_ * D_;
    float* hbuf= ffn + (size_t)S_ * D_;
    float* tok_w = hbuf + (size_t)S_ * HID_;
    float* wlist = tok_w + (size_t)S_ * 2;
    int* tok_e   = (int*)(wlist + (size_t)S_ * 2);
    int* list    = tok_e + 2 * S_;
    int* counts  = list + 2 * S_;
    int* bases   = counts + E_;
    int* cursors = bases + E_;

    dim3 blk(256);

    zero_counts<<<dim3(1), dim3(64), 0, stream>>>(counts);

    // Attention projections
    sgemm_nn<<<dim3(D_ / 128, S_ / 128), blk, 0, stream>>>(src, Wq, q, S_, D_, D_);
    sgemm_nn<<<dim3(DC_ / 128, S_ / 128), blk, 0, stream>>>(src, Wk_c, kc, S_, DC_, D_);
    sgemm_nn<<<dim3(DC_ / 128, S_ / 128), blk, 0, stream>>>(src, Wv_c, vc, S_, DC_, D_);
    sgemm_nn<<<dim3(D_ / 128, S_ / 128), blk, 0, stream>>>(kc, Wk, k, S_, D_, DC_);
    sgemm_nn<<<dim3(D_ / 128, S_ / 128), blk, 0, stream>>>(vc, Wv, v, S_, D_, DC_);

    rope_kernel<<<dim3(S_ * (D_ / 2) / 256), blk, 0, stream>>>(q);
    rope_kernel<<<dim3(S_ * (D_ / 2) / 256), blk, 0, stream>>>(k);

    attn_kernel<<<dim3(T_ / 64, B_ * H_), blk, 0, stream>>>(q, k, v, sa);

    sgemm_nn<<<dim3(D_ / 128, S_ / 128), blk, 0, stream>>>(sa, Wo, q, S_, D_, D_);  // q reused = attn proj
    rmsnorm_res<<<dim3(S_), blk, 0, stream>>>(src, q, n1w, x1);

    // Shared FFN
    sgemm_nn<<<dim3(2 * HID_ / 128, S_ / 128), blk, 0, stream>>>(x1, Wsin, mid, S_, 2 * HID_, D_);
    swiglu_kernel<<<dim3(S_ * HID_ / 256), blk, 0, stream>>>(mid, hbuf);
    sgemm_nn<<<dim3(D_ / 128, S_ / 128), blk, 0, stream>>>(hbuf, Wsout, ffn, S_, D_, HID_);

    // Gating + routing lists
    gate_kernel<<<dim3(S_ / 4), blk, 0, stream>>>(x1, Wg, We, gb, eb, tok_e, tok_w, counts);
    scan_kernel<<<dim3(1), dim3(1), 0, stream>>>(counts, bases, cursors);
    scatter_kernel<<<dim3(S_ / 256), blk, 0, stream>>>(tok_e, tok_w, cursors, list, wlist);

    // Routed experts (top-2 sparse)
    sgemm_nn<<<dim3(2 * HID_ / 128, S_ / 128), blk, 0, stream>>>(x1, W1, mid, S_, 2 * HID_, D_);
    swiglu_kernel<<<dim3(S_ * HID_ / 256), blk, 0, stream>>>(mid, hbuf);
    routed_gemm<<<dim3(D_ / 128, E_ * 32), blk, 0, stream>>>(hbuf, W2, list, wlist, bases, counts, ffn);

    // Final residual + norm
    rmsnorm_res<<<dim3(S_), blk, 0, stream>>>(x1, ffn, n2w, out);
}

// Round 2
// 2024.491 us; speedup vs baseline: 2.1582x; 2.1582x over previous
//
#include <hip/hip_runtime.h>
#include <math.h>

#define D_    1024
#define H_    16
#define DH_   64
#define DC_   256
#define HID_  2048
#define E_    8
#define B_    2
#define T_    2048
#define S_    4096
#define EPS_  1e-6f

typedef unsigned short u16;
typedef short bf16x8 __attribute__((ext_vector_type(8)));
typedef float f32x4 __attribute__((ext_vector_type(4)));

__device__ __forceinline__ float b2f(u16 u) {
    return __uint_as_float(((unsigned int)u) << 16);
}
__device__ __forceinline__ u16 f2b(float f) {
    unsigned int u = __float_as_uint(f);
    u += 0x7FFF + ((u >> 16) & 1);          // round-to-nearest-even
    return (u16)(u >> 16);
}
__device__ __forceinline__ void g2l16(const u16* g, u16* l) {
    __builtin_amdgcn_global_load_lds(
        (const __attribute__((address_space(1))) void*)g,
        (__attribute__((address_space(3))) void*)l, 16, 0, 0);
}

// ---------------------------------------------------------------------------
// Transpose + fp32->bf16 convert: in (K,N) fp32 -> out (N,K) bf16.
// grid (N/32, K/32, Z), block 256.
// ---------------------------------------------------------------------------
__global__ __launch_bounds__(256) void conv_t(const float* __restrict__ in,
                                              u16* __restrict__ out,
                                              int K, int N,
                                              long inZ, long outZ) {
    in  += (long)blockIdx.z * inZ;
    out += (long)blockIdx.z * outZ;
    __shared__ float t[32][33];
    const int n0 = blockIdx.x * 32, k0 = blockIdx.y * 32;
    const int tx = threadIdx.x & 31, ty = threadIdx.x >> 5;
#pragma unroll
    for (int i = 0; i < 4; i++)
        t[ty + 8 * i][tx] = in[(long)(k0 + ty + 8 * i) * N + n0 + tx];
    __syncthreads();
#pragma unroll
    for (int i = 0; i < 4; i++)
        out[(long)(n0 + ty + 8 * i) * K + k0 + tx] = f2b(t[tx][ty + 8 * i]);
}

// Elementwise fp32 -> bf16 (n multiple of 1024)
__global__ __launch_bounds__(256) void convert_bf16(const float* __restrict__ in,
                                                    u16* __restrict__ out, int n4) {
    int i = blockIdx.x * 256 + threadIdx.x;
    if (i >= n4) return;
    float4 f = ((const float4*)in)[i];
    ushort4 o;
    o.x = f2b(f.x); o.y = f2b(f.y); o.z = f2b(f.z); o.w = f2b(f.w);
    ((ushort4*)out)[i] = o;
}

// ---------------------------------------------------------------------------
// bf16 MFMA GEMM: C(M,N) = A(M,K) @ Bt(N,K)^T. 128x128 tile, BK=32,
// 256 thr = 4 waves (2x2), each wave 64x64 via 4x4 of 16x16x32 MFMA.
// OUTMODE: 0 = fp32 out, 1 = bf16 out.
// ---------------------------------------------------------------------------
template<int OUTMODE>
__global__ __launch_bounds__(256) void gemm_bf16(const u16* __restrict__ A,
                                                 const u16* __restrict__ Bt,
                                                 void* __restrict__ Cp,
                                                 int N, int K) {
    __shared__ u16 As[128 * 32];
    __shared__ u16 Bs[128 * 32];
    const int tid  = threadIdx.x;
    const int lane = tid & 63;
    const int wv   = tid >> 6;
    const int wm   = wv >> 1, wn = wv & 1;
    const long row0 = (long)blockIdx.y * 128;
    const long col0 = (long)blockIdx.x * 128;

    f32x4 acc[4][4];
#pragma unroll
    for (int i = 0; i < 4; i++)
#pragma unroll
        for (int j = 0; j < 4; j++) acc[i][j] = (f32x4){0.f, 0.f, 0.f, 0.f};

    const int sr = tid >> 2;
    const int sc = (tid & 3) << 3;
    const u16* Ag  = A  + (row0 + sr) * (long)K + sc;
    const u16* Ag2 = Ag + 64 * (long)K;
    const u16* Bg  = Bt + (col0 + sr) * (long)K + sc;
    const u16* Bg2 = Bg + 64 * (long)K;
    u16* lA  = As + tid * 8;
    u16* lA2 = As + 2048 + tid * 8;
    u16* lB  = Bs + tid * 8;
    u16* lB2 = Bs + 2048 + tid * 8;

    const int fl = lane & 15;
    const int fk = (lane >> 4) << 3;
    const u16* ArA = As + (wm * 64 + fl) * 32 + fk;
    const u16* BrB = Bs + (wn * 64 + fl) * 32 + fk;

    for (int k0 = 0; k0 < K; k0 += 32) {
        __syncthreads();
        g2l16(Ag + k0, lA);
        g2l16(Ag2 + k0, lA2);
        g2l16(Bg + k0, lB);
        g2l16(Bg2 + k0, lB2);
        __syncthreads();
        bf16x8 af[4], bfr[4];
#pragma unroll
        for (int mi = 0; mi < 4; mi++) af[mi]  = *(const bf16x8*)(ArA + mi * 512);
#pragma unroll
        for (int ni = 0; ni < 4; ni++) bfr[ni] = *(const bf16x8*)(BrB + ni * 512);
#pragma unroll
        for (int mi = 0; mi < 4; mi++)
#pragma unroll
            for (int ni = 0; ni < 4; ni++)
                acc[mi][ni] = __builtin_amdgcn_mfma_f32_16x16x32_bf16(
                    af[mi], bfr[ni], acc[mi][ni], 0, 0, 0);
    }

    const int cr = (lane >> 4) << 2;
    const int cc = lane & 15;
#pragma unroll
    for (int mi = 0; mi < 4; mi++) {
#pragma unroll
        for (int r = 0; r < 4; r++) {
            long grow = row0 + wm * 64 + mi * 16 + cr + r;
#pragma unroll
            for (int ni = 0; ni < 4; ni++) {
                long gcol = col0 + wn * 64 + ni * 16 + cc;
                float v = acc[mi][ni][r];
                if (OUTMODE == 0) ((float*)Cp)[grow * N + gcol] = v;
                else              ((u16*)Cp)[grow * N + gcol] = f2b(v);
            }
        }
    }
}

// ---------------------------------------------------------------------------
// Routed-expert bf16 MFMA GEMM: gathered A rows from Hh (S,HID) via token list,
// Bt = W2T (E, D, HID) bf16 pre-transposed, scaled atomicAdd into Cout (S,D).
// grid (D/128, E*32).
// ---------------------------------------------------------------------------
__global__ __launch_bounds__(256) void routed_gemm(const u16* __restrict__ Hh,
                                                   const u16* __restrict__ W2T,
                                                   const int* __restrict__ list,
                                                   const float* __restrict__ wlist,
                                                   const int* __restrict__ bases,
                                                   const int* __restrict__ counts,
                                                   float* __restrict__ Cout) {
    const int e    = blockIdx.y >> 5;
    const int tile = blockIdx.y & 31;
    const int cnt  = counts[e];
    if (tile * 128 >= cnt) return;
    const int base = bases[e];

    __shared__ u16 As[128 * 32];
    __shared__ u16 Bs[128 * 32];
    __shared__ int   toks[128];
    __shared__ float wrow[128];

    const int tid = threadIdx.x;
    if (tid < 128) {
        int ridx = tile * 128 + tid;
        if (ridx < cnt) { toks[tid] = list[base + ridx]; wrow[tid] = wlist[base + ridx]; }
        else            { toks[tid] = -1;                wrow[tid] = 0.f; }
    }
    __syncthreads();

    const int lane = tid & 63;
    const int wv   = tid >> 6;
    const int wm   = wv >> 1, wn = wv & 1;
    const long col0 = (long)blockIdx.x * 128;

    f32x4 acc[4][4];
#pragma unroll
    for (int i = 0; i < 4; i++)
#pragma unroll
        for (int j = 0; j < 4; j++) acc[i][j] = (f32x4){0.f, 0.f, 0.f, 0.f};

    const int sr = tid >> 2;
    const int sc = (tid & 3) << 3;
    const int t1 = toks[sr], t2 = toks[sr + 64];
    const u16* Ag  = Hh + (long)(t1 < 0 ? 0 : t1) * HID_ + sc;
    const u16* Ag2 = Hh + (long)(t2 < 0 ? 0 : t2) * HID_ + sc;
    const u16* Bg  = W2T + (long)e * D_ * HID_ + (col0 + sr) * (long)HID_ + sc;
    const u16* Bg2 = Bg + 64 * (long)HID_;
    u16* lA  = As + tid * 8;
    u16* lA2 = As + 2048 + tid * 8;
    u16* lB  = Bs + tid * 8;
    u16* lB2 = Bs + 2048 + tid * 8;

    const int fl = lane & 15;
    const int fk = (lane >> 4) << 3;
    const u16* ArA = As + (wm * 64 + fl) * 32 + fk;
    const u16* BrB = Bs + (wn * 64 + fl) * 32 + fk;

    for (int k0 = 0; k0 < HID_; k0 += 32) {
        __syncthreads();
        g2l16(Ag + k0, lA);
        g2l16(Ag2 + k0, lA2);
        g2l16(Bg + k0, lB);
        g2l16(Bg2 + k0, lB2);
        __syncthreads();
        bf16x8 af[4], bfr[4];
#pragma unroll
        for (int mi = 0; mi < 4; mi++) af[mi]  = *(const bf16x8*)(ArA + mi * 512);
#pragma unroll
        for (int ni = 0; ni < 4; ni++) bfr[ni] = *(const bf16x8*)(BrB + ni * 512);
#pragma unroll
        for (int mi = 0; mi < 4; mi++)
#pragma unroll
            for (int ni = 0; ni < 4; ni++)
                acc[mi][ni] = __builtin_amdgcn_mfma_f32_16x16x32_bf16(
                    af[mi], bfr[ni], acc[mi][ni], 0, 0, 0);
    }

    const int cr = (lane >> 4) << 2;
    const int cc = lane & 15;
#pragma unroll
    for (int mi = 0; mi < 4; mi++) {
#pragma unroll
        for (int r = 0; r < 4; r++) {
            int rr = wm * 64 + mi * 16 + cr + r;
            int tk = toks[rr];
            if (tk < 0) continue;
            float wvw = wrow[rr];
            float* crow = Cout + (long)tk * D_ + col0 + wn * 64;
#pragma unroll
            for (int ni = 0; ni < 4; ni++)
                atomicAdd(crow + ni * 16 + cc, acc[mi][ni][r] * wvw);
        }
    }
}

// ---------------------------------------------------------------------------
// RoPE in place on bf16 (S,D) buffer. One thread per (even,odd) pair.
// ---------------------------------------------------------------------------
__global__ __launch_bounds__(256) void rope_kernel(u16* __restrict__ x) {
    long p = (long)blockIdx.x * 256 + threadIdx.x;   // S_*D_/2 pairs
    int s = (int)(p / (D_ / 2));
    int r = (int)(p % (D_ / 2));
    int t = s & (T_ - 1);
    int d = r * 2;
    int i = (d & (DH_ - 1)) >> 1;
    float ang = (float)t * powf(10000.f, -(float)i / 32.f);
    float sn, cs;
    sincosf(ang, &sn, &cs);
    u16* px = x + (long)s * D_ + d;
    float x1 = b2f(px[0]), x2 = b2f(px[1]);
    px[0] = f2b(x1 * cs - x2 * sn);
    px[1] = f2b(x1 * sn + x2 * cs);
}

// ---------------------------------------------------------------------------
// Flash attention, register-blocked. grid (T/64, B*H), 256 threads.
// LDS: Qt/Kt/Vt transposed [d][row], Ps [kc][q]; all strides 64 -> 64 KB.
// Thread (tq=tid>>4, tk=tid&15) owns 4 q-rows x 4 cols (k-cols then d-cols).
// ---------------------------------------------------------------------------
__global__ __launch_bounds__(256) void attn_kernel(const u16* __restrict__ qb,
                                                   const u16* __restrict__ kb,
                                                   const u16* __restrict__ vb,
                                                   u16* __restrict__ sab) {
    __shared__ float Qt[64][64];
    __shared__ float Kt[64][64];
    __shared__ float Vt[64][64];
    __shared__ float Ps[64][64];
    const int tid = threadIdx.x;
    const int lr = tid >> 2;
    const int dc = (tid & 3) << 4;
    const int b = blockIdx.y >> 4, h = blockIdx.y & 15;
    const long base = (long)b * T_ + blockIdx.x * 64;

    {
        const u16* qp = qb + (base + lr) * D_ + h * DH_ + dc;
#pragma unroll
        for (int j = 0; j < 16; j++) Qt[dc + j][lr] = b2f(qp[j]);
    }

    const int tq = tid >> 4;
    const int tk = tid & 15;
    float m_[4], l_[4], O[4][4];
#pragma unroll
    for (int i = 0; i < 4; i++) {
        m_[i] = -1e30f; l_[i] = 0.f;
#pragma unroll
        for (int j = 0; j < 4; j++) O[i][j] = 0.f;
    }

    const u16* kp0 = kb + (long)b * T_ * D_ + h * DH_ + dc;
    const u16* vp0 = vb + (long)b * T_ * D_ + h * DH_ + dc;

    for (int kt = 0; kt < T_ / 64; kt++) {
        __syncthreads();
        {
            const u16* kp = kp0 + (long)(kt * 64 + lr) * D_;
            const u16* vp = vp0 + (long)(kt * 64 + lr) * D_;
#pragma unroll
            for (int j = 0; j < 16; j++) {
                Kt[dc + j][lr] = b2f(kp[j]);
                Vt[dc + j][lr] = b2f(vp[j]);
            }
        }
        __syncthreads();

        float s[4][4];
#pragma unroll
        for (int i = 0; i < 4; i++)
#pragma unroll
            for (int j = 0; j < 4; j++) s[i][j] = 0.f;

#pragma unroll 8
        for (int d = 0; d < 64; d++) {
            float4 aq = *(const float4*)&Qt[d][tq * 4];
            float4 ak = *(const float4*)&Kt[d][tk * 4];
            float av[4] = {aq.x, aq.y, aq.z, aq.w};
            float bv[4] = {ak.x, ak.y, ak.z, ak.w};
#pragma unroll
            for (int i = 0; i < 4; i++)
#pragma unroll
                for (int j = 0; j < 4; j++) s[i][j] += av[i] * bv[j];
        }

        const float scale = 0.125f;
        float rm[4], alpha[4], psum[4];
#pragma unroll
        for (int i = 0; i < 4; i++)
            rm[i] = fmaxf(fmaxf(s[i][0], s[i][1]), fmaxf(s[i][2], s[i][3])) * scale;
#pragma unroll
        for (int off = 1; off < 16; off <<= 1)
#pragma unroll
            for (int i = 0; i < 4; i++) rm[i] = fmaxf(rm[i], __shfl_xor(rm[i], off));
#pragma unroll
        for (int i = 0; i < 4; i++) {
            float nm = fmaxf(m_[i], rm[i]);
            alpha[i] = __expf(m_[i] - nm);
            m_[i] = nm;
            psum[i] = 0.f;
        }
#pragma unroll
        for (int i = 0; i < 4; i++)
#pragma unroll
            for (int j = 0; j < 4; j++) {
                float pij = __expf(s[i][j] * scale - m_[i]);
                Ps[tk * 4 + j][tq * 4 + i] = pij;
                psum[i] += pij;
            }
#pragma unroll
        for (int off = 1; off < 16; off <<= 1)
#pragma unroll
            for (int i = 0; i < 4; i++) psum[i] += __shfl_xor(psum[i], off);
#pragma unroll
        for (int i = 0; i < 4; i++) {
            l_[i] = l_[i] * alpha[i] + psum[i];
#pragma unroll
            for (int j = 0; j < 4; j++) O[i][j] *= alpha[i];
        }
        __syncthreads();

#pragma unroll 4
        for (int kc = 0; kc < 64; kc++) {
            float4 pp = *(const float4*)&Ps[kc][tq * 4];
            float pv[4] = {pp.x, pp.y, pp.z, pp.w};
            float vv[4];
#pragma unroll
            for (int j = 0; j < 4; j++) vv[j] = Vt[tk * 4 + j][kc];
#pragma unroll
            for (int i = 0; i < 4; i++)
#pragma unroll
                for (int j = 0; j < 4; j++) O[i][j] += pv[i] * vv[j];
        }
    }

#pragma unroll
    for (int i = 0; i < 4; i++) {
        float inv = 1.f / l_[i];
        u16* op = sab + (base + tq * 4 + i) * D_ + h * DH_ + tk * 4;
#pragma unroll
        for (int j = 0; j < 4; j++) op[j] = f2b(O[i][j] * inv);
    }
}

// ---------------------------------------------------------------------------
// Residual add + RMSNorm. BF=1 additionally writes bf16 copy.
// ---------------------------------------------------------------------------
template<int BF>
__global__ __launch_bounds__(256) void rmsnorm_res(const float* __restrict__ a,
                                                   const float* __restrict__ b,
                                                   const float* __restrict__ w,
                                                   float* __restrict__ outf,
                                                   u16* __restrict__ outb) {
    const int s = blockIdx.x;
    const float* ar = a + (long)s * D_;
    const float* br = b + (long)s * D_;
    float y[4];
    float ss = 0.f;
#pragma unroll
    for (int kx = 0; kx < 4; kx++) {
        int j = threadIdx.x + kx * 256;
        y[kx] = ar[j] + br[j];
        ss += y[kx] * y[kx];
    }
    __shared__ float red[4];
#pragma unroll
    for (int off = 32; off > 0; off >>= 1) ss += __shfl_down(ss, off);
    int lane = threadIdx.x & 63, wv = threadIdx.x >> 6;
    if (lane == 0) red[wv] = ss;
    __syncthreads();
    float tot = red[0] + red[1] + red[2] + red[3];
    float scl = rsqrtf(tot / (float)D_ + EPS_);
    float* orow = outf + (long)s * D_;
#pragma unroll
    for (int kx = 0; kx < 4; kx++) {
        int j = threadIdx.x + kx * 256;
        float v = y[kx] * scl * w[j];
        orow[j] = v;
        if (BF) outb[(long)s * D_ + j] = f2b(v);
    }
}

// SwiGLU: bf16 mid (S, 2*HID) -> bf16 h (S, HID)
__global__ __launch_bounds__(256) void swiglu_kernel(const u16* __restrict__ mid,
                                                     u16* __restrict__ h) {
    long idx = (long)blockIdx.x * 256 + threadIdx.x;
    long srow = idx / HID_;
    int j = (int)(idx % HID_);
    float a  = b2f(mid[srow * (2 * HID_) + j]);
    float bb = b2f(mid[srow * (2 * HID_) + HID_ + j]);
    float sig = 1.f / (1.f + __expf(-a));
    h[idx] = f2b(a * sig * bb);
}

// ---------------------------------------------------------------------------
// Gating (fp32): one wave per token.
// ---------------------------------------------------------------------------
__global__ __launch_bounds__(256) void gate_kernel(const float* __restrict__ x,
                                                   const float* __restrict__ Wg,
                                                   const float* __restrict__ We,
                                                   const float* __restrict__ gb,
                                                   const float* __restrict__ eb,
                                                   int* __restrict__ tok_e,
                                                   float* __restrict__ tok_w,
                                                   int* __restrict__ counts) {
    const int wave = threadIdx.x >> 6;
    const int lane = threadIdx.x & 63;
    const int s = blockIdx.x * 4 + wave;
    const float* xr = x + (long)s * D_;
    float g0 = 0.f, g1 = 0.f;
    float ee[8];
#pragma unroll
    for (int e = 0; e < 8; e++) ee[e] = 0.f;
    for (int j = lane; j < D_; j += 64) {
        float xv = xr[j];
        g0 += xv * Wg[j * 2 + 0];
        g1 += xv * Wg[j * 2 + 1];
#pragma unroll
        for (int e = 0; e < 8; e++) ee[e] += xv * We[j * 8 + e];
    }
#pragma unroll
    for (int off = 32; off > 0; off >>= 1) {
        g0 += __shfl_down(g0, off);
        g1 += __shfl_down(g1, off);
#pragma unroll
        for (int e = 0; e < 8; e++) ee[e] += __shfl_down(ee[e], off);
    }
    if (lane == 0) {
        g0 += gb[0];
        g1 += gb[1];
        int gidx = (g1 > g0) ? 1 : 0;
        float gm = fmaxf(g0, g1);
        float p0 = expf(g0 - gm), p1 = expf(g1 - gm);
        float gprob = (gidx ? p1 : p0) / (p0 + p1);
        int base = gidx * 4;
        float pe[4];
        float em = -1e30f;
#pragma unroll
        for (int i = 0; i < 4; i++) {
            pe[i] = ee[base + i] + eb[base + i];
            em = fmaxf(em, pe[i]);
        }
        float sum = 0.f;
#pragma unroll
        for (int i = 0; i < 4; i++) { pe[i] = expf(pe[i] - em); sum += pe[i]; }
        float inv = gprob / sum;
#pragma unroll
        for (int i = 0; i < 4; i++) pe[i] *= inv;
        int i1 = 0;
        for (int i = 1; i < 4; i++) if (pe[i] > pe[i1]) i1 = i;
        int i2 = -1;
        for (int i = 0; i < 4; i++) {
            if (i == i1) continue;
            if (i2 < 0 || pe[i] > pe[i2]) i2 = i;
        }
        tok_e[s * 2 + 0] = base + i1;
        tok_e[s * 2 + 1] = base + i2;
        tok_w[s * 2 + 0] = pe[i1];
        tok_w[s * 2 + 1] = pe[i2];
        atomicAdd(&counts[base + i1], 1);
        atomicAdd(&counts[base + i2], 1);
    }
}

__global__ void zero_counts(int* counts) {
    if (threadIdx.x < E_) counts[threadIdx.x] = 0;
}

__global__ void scan_kernel(const int* __restrict__ counts,
                            int* __restrict__ bases,
                            int* __restrict__ cursors) {
    if (threadIdx.x == 0 && blockIdx.x == 0) {
        int acc = 0;
        for (int e = 0; e < E_; e++) {
            bases[e] = acc; cursors[e] = acc; acc += counts[e];
        }
    }
}

__global__ __launch_bounds__(256) void scatter_kernel(const int* __restrict__ tok_e,
                                                      const float* __restrict__ tok_w,
                                                      int* __restrict__ cursors,
                                                      int* __restrict__ list,
                                                      float* __restrict__ wlist) {
    int s = blockIdx.x * 256 + threadIdx.x;
    if (s >= S_) return;
#pragma unroll
    for (int t = 0; t < 2; t++) {
        int e = tok_e[s * 2 + t];
        int pos = atomicAdd(&cursors[e], 1);
        list[pos] = s;
        wlist[pos] = tok_w[s * 2 + t];
    }
}

// ---------------------------------------------------------------------------
extern "C" void kernel_launch(void* const* d_in, const int* in_sizes, int n_in,
                              void* d_out, int out_size, void* d_ws, size_t ws_size,
                              hipStream_t stream) {
    const float* src  = (const float*)d_in[0];
    const float* Wq   = (const float*)d_in[1];
    const float* Wk_c = (const float*)d_in[2];
    const float* Wv_c = (const float*)d_in[3];
    const float* Wk   = (const float*)d_in[4];
    const float* Wv   = (const float*)d_in[5];
    const float* Wo   = (const float*)d_in[6];
    const float* Wsin = (const float*)d_in[7];
    const float* Wsout= (const float*)d_in[8];
    const float* W1   = (const float*)d_in[9];
    const float* W2   = (const float*)d_in[10];
    const float* Wg   = (const float*)d_in[11];
    const float* We   = (const float*)d_in[12];
    const float* gb   = (const float*)d_in[13];
    const float* eb   = (const float*)d_in[14];
    const float* n1w  = (const float*)d_in[15];
    const float* n2w  = (const float*)d_in[16];
    float* out = (float*)d_out;

    const size_t MB = 1u << 20;
    char* w8 = (char*)d_ws;
    // region0 [0,36MB): qb,kb,vb,kcb,vcb,srcb -> later o_proj (fp32,16MB) -> later mid (32MB) / W2T (32MB)
    u16*  qb    = (u16*)(w8);
    u16*  kbuf  = (u16*)(w8 + 8 * MB);
    u16*  vbuf  = (u16*)(w8 + 16 * MB);
    u16*  kcb   = (u16*)(w8 + 24 * MB);
    u16*  vcb   = (u16*)(w8 + 26 * MB);
    u16*  srcb  = (u16*)(w8 + 28 * MB);
    float* oproj= (float*)(w8);
    u16*  midb  = (u16*)(w8);
    u16*  w2t   = (u16*)(w8);
    u16*  sab   = (u16*)(w8 + 36 * MB);
    float* x1   = (float*)(w8 + 44 * MB);
    float* ffn  = (float*)(w8 + 60 * MB);
    u16*  x1b   = (u16*)(w8 + 76 * MB);
    u16*  hbuf  = (u16*)(w8 + 84 * MB);
    u16*  WqT   = (u16*)(w8 + 100 * MB);
    u16*  WkcT  = (u16*)(w8 + 102 * MB);
    u16*  WvcT  = (u16*)(w8 + 102 * MB + 512 * 1024);
    u16*  WkT   = (u16*)(w8 + 103 * MB);
    u16*  WvT   = (u16*)(w8 + 103 * MB + 512 * 1024);
    u16*  WoT   = (u16*)(w8 + 104 * MB);
    u16*  WsinT = (u16*)(w8 + 106 * MB);
    u16*  WsoutT= (u16*)(w8 + 114 * MB);
    u16*  W1T   = (u16*)(w8 + 118 * MB);
    float* tokw = (float*)(w8 + 126 * MB);
    float* wlist = tokw + 2 * S_;
    int* toke   = (int*)(wlist + 2 * S_);
    int* list   = toke + 2 * S_;
    int* counts = list + 2 * S_;
    int* bases  = counts + E_;
    int* cursors= bases + E_;

    dim3 blk(256);

    zero_counts<<<dim3(1), dim3(64), 0, stream>>>(counts);

    // Weight conversions (fp32 (K,N) -> bf16 (N,K))
    conv_t<<<dim3(32, 32), blk, 0, stream>>>(Wq,    WqT,    1024, 1024, 0, 0);
    conv_t<<<dim3(8, 32),  blk, 0, stream>>>(Wk_c,  WkcT,   1024, 256,  0, 0);
    conv_t<<<dim3(8, 32),  blk, 0, stream>>>(Wv_c,  WvcT,   1024, 256,  0, 0);
    conv_t<<<dim3(32, 8),  blk, 0, stream>>>(Wk,    WkT,    256,  1024, 0, 0);
    conv_t<<<dim3(32, 8),  blk, 0, stream>>>(Wv,    WvT,    256,  1024, 0, 0);
    conv_t<<<dim3(32, 32), blk, 0, stream>>>(Wo,    WoT,    1024, 1024, 0, 0);
    conv_t<<<dim3(128, 32),blk, 0, stream>>>(Wsin,  WsinT,  1024, 4096, 0, 0);
    conv_t<<<dim3(32, 64), blk, 0, stream>>>(Wsout, WsoutT, 2048, 1024, 0, 0);
    conv_t<<<dim3(128, 32),blk, 0, stream>>>(W1,    W1T,    1024, 4096, 0, 0);
    convert_bf16<<<dim3(S_ * D_ / 4 / 256), blk, 0, stream>>>(src, srcb, S_ * D_ / 4);

    // QKV projections (bf16 MFMA)
    gemm_bf16<1><<<dim3(8, 32), blk, 0, stream>>>(srcb, WqT,  qb,   1024, 1024);
    gemm_bf16<1><<<dim3(2, 32), blk, 0, stream>>>(srcb, WkcT, kcb,  256,  1024);
    gemm_bf16<1><<<dim3(2, 32), blk, 0, stream>>>(srcb, WvcT, vcb,  256,  1024);
    gemm_bf16<1><<<dim3(8, 32), blk, 0, stream>>>(kcb,  WkT,  kbuf, 1024, 256);
    gemm_bf16<1><<<dim3(8, 32), blk, 0, stream>>>(vcb,  WvT,  vbuf, 1024, 256);

    rope_kernel<<<dim3(S_ * (D_ / 2) / 256), blk, 0, stream>>>(qb);
    rope_kernel<<<dim3(S_ * (D_ / 2) / 256), blk, 0, stream>>>(kbuf);

    attn_kernel<<<dim3(T_ / 64, B_ * H_), blk, 0, stream>>>(qb, kbuf, vbuf, sab);

    gemm_bf16<0><<<dim3(8, 32), blk, 0, stream>>>(sab, WoT, oproj, 1024, 1024);
    rmsnorm_res<1><<<dim3(S_), blk, 0, stream>>>(src, oproj, n1w, x1, x1b);

    // Shared FFN
    gemm_bf16<1><<<dim3(32, 32), blk, 0, stream>>>(x1b, WsinT, midb, 4096, 1024);
    swiglu_kernel<<<dim3(S_ * HID_ / 256), blk, 0, stream>>>(midb, hbuf);
    gemm_bf16<0><<<dim3(8, 32), blk, 0, stream>>>(hbuf, WsoutT, ffn, 1024, 2048);

    // Gating
    gate_kernel<<<dim3(S_ / 4), blk, 0, stream>>>(x1, Wg, We, gb, eb, toke, tokw, counts);
    scan_kernel<<<dim3(1), dim3(1), 0, stream>>>(counts, bases, cursors);
    scatter_kernel<<<dim3(S_ / 256), blk, 0, stream>>>(toke, tokw, cursors, list, wlist);

    // Routed experts
    gemm_bf16<1><<<dim3(32, 32), blk, 0, stream>>>(x1b, W1T, midb, 4096, 1024);
    swiglu_kernel<<<dim3(S_ * HID_ / 256), blk, 0, stream>>>(midb, hbuf);
    conv_t<<<dim3(32, 64, 8), blk, 0, stream>>>(W2, w2t, 2048, 1024,
                                                (long)HID_ * D_, (long)D_ * HID_);
    routed_gemm<<<dim3(8, E_ * 32), blk, 0, stream>>>(hbuf, w2t, list, wlist,
                                                      bases, counts, ffn);

    rmsnorm_res<0><<<dim3(S_), blk, 0, stream>>>(x1, ffn, n2w, out, (u16*)nullptr);
}

// Round 3
// 871.200 us; speedup vs baseline: 5.0151x; 2.3238x over previous
//
#include <hip/hip_runtime.h>
#include <math.h>

#define D_    1024
#define H_    16
#define DH_   64
#define DC_   256
#define HID_  2048
#define E_    8
#define B_    2
#define T_    2048
#define S_    4096
#define EPS_  1e-6f

typedef unsigned short u16;
typedef short bf16x8 __attribute__((ext_vector_type(8)));
typedef float f32x4 __attribute__((ext_vector_type(4)));

__device__ __forceinline__ float b2f(u16 u) {
    return __uint_as_float(((unsigned int)u) << 16);
}
__device__ __forceinline__ u16 f2b(float f) {
    unsigned int u = __float_as_uint(f);
    u += 0x7FFF + ((u >> 16) & 1);          // round-to-nearest-even
    return (u16)(u >> 16);
}
__device__ __forceinline__ void g2l16(const u16* g, u16* l) {
    __builtin_amdgcn_global_load_lds(
        (const __attribute__((address_space(1))) void*)g,
        (__attribute__((address_space(3))) void*)l, 16, 0, 0);
}

// ---------------------------------------------------------------------------
// Transpose + fp32->bf16 convert: in (K,N) fp32 -> out (N,K) bf16.
// ---------------------------------------------------------------------------
__global__ __launch_bounds__(256) void conv_t(const float* __restrict__ in,
                                              u16* __restrict__ out,
                                              int K, int N,
                                              long inZ, long outZ) {
    in  += (long)blockIdx.z * inZ;
    out += (long)blockIdx.z * outZ;
    __shared__ float t[32][33];
    const int n0 = blockIdx.x * 32, k0 = blockIdx.y * 32;
    const int tx = threadIdx.x & 31, ty = threadIdx.x >> 5;
#pragma unroll
    for (int i = 0; i < 4; i++)
        t[ty + 8 * i][tx] = in[(long)(k0 + ty + 8 * i) * N + n0 + tx];
    __syncthreads();
#pragma unroll
    for (int i = 0; i < 4; i++)
        out[(long)(n0 + ty + 8 * i) * K + k0 + tx] = f2b(t[tx][ty + 8 * i]);
}

// bf16 transpose V (S,D) per-head -> Vt [bh][d=64][T]
__global__ __launch_bounds__(256) void vt_conv(const u16* __restrict__ v,
                                               u16* __restrict__ vt) {
    __shared__ u16 t[32][34];
    const int bh = blockIdx.z;
    const int b = bh >> 4, h = bh & 15;
    const int t0 = blockIdx.x * 32, d0 = blockIdx.y * 32;
    const int tx = threadIdx.x & 31, ty = threadIdx.x >> 5;
#pragma unroll
    for (int i = 0; i < 4; i++)
        t[ty + 8 * i][tx] = v[((long)b * T_ + t0 + ty + 8 * i) * D_ + h * 64 + d0 + tx];
    __syncthreads();
#pragma unroll
    for (int i = 0; i < 4; i++)
        vt[((long)bh * 64 + d0 + ty + 8 * i) * T_ + t0 + tx] = t[tx][ty + 8 * i];
}

// Elementwise fp32 -> bf16
__global__ __launch_bounds__(256) void convert_bf16(const float* __restrict__ in,
                                                    u16* __restrict__ out, int n4) {
    int i = blockIdx.x * 256 + threadIdx.x;
    if (i >= n4) return;
    float4 f = ((const float4*)in)[i];
    ushort4 o;
    o.x = f2b(f.x); o.y = f2b(f.y); o.z = f2b(f.z); o.w = f2b(f.w);
    ((ushort4*)out)[i] = o;
}

// ---------------------------------------------------------------------------
// bf16 MFMA GEMM: C(M,N) = A(M,K) @ Bt(N,K)^T. 128x128, BK=32, 4 waves.
// ---------------------------------------------------------------------------
template<int OUTMODE>
__global__ __launch_bounds__(256) void gemm_bf16(const u16* __restrict__ A,
                                                 const u16* __restrict__ Bt,
                                                 void* __restrict__ Cp,
                                                 int N, int K) {
    __shared__ u16 As[128 * 32];
    __shared__ u16 Bs[128 * 32];
    const int tid  = threadIdx.x;
    const int lane = tid & 63;
    const int wv   = tid >> 6;
    const int wm   = wv >> 1, wn = wv & 1;
    const long row0 = (long)blockIdx.y * 128;
    const long col0 = (long)blockIdx.x * 128;

    f32x4 acc[4][4];
#pragma unroll
    for (int i = 0; i < 4; i++)
#pragma unroll
        for (int j = 0; j < 4; j++) acc[i][j] = (f32x4){0.f, 0.f, 0.f, 0.f};

    const int sr = tid >> 2;
    const int sc = (tid & 3) << 3;
    const u16* Ag  = A  + (row0 + sr) * (long)K + sc;
    const u16* Ag2 = Ag + 64 * (long)K;
    const u16* Bg  = Bt + (col0 + sr) * (long)K + sc;
    const u16* Bg2 = Bg + 64 * (long)K;
    u16* lA  = As + tid * 8;
    u16* lA2 = As + 2048 + tid * 8;
    u16* lB  = Bs + tid * 8;
    u16* lB2 = Bs + 2048 + tid * 8;

    const int fl = lane & 15;
    const int fk = (lane >> 4) << 3;
    const u16* ArA = As + (wm * 64 + fl) * 32 + fk;
    const u16* BrB = Bs + (wn * 64 + fl) * 32 + fk;

    for (int k0 = 0; k0 < K; k0 += 32) {
        __syncthreads();
        g2l16(Ag + k0, lA);
        g2l16(Ag2 + k0, lA2);
        g2l16(Bg + k0, lB);
        g2l16(Bg2 + k0, lB2);
        __syncthreads();
        bf16x8 af[4], bfr[4];
#pragma unroll
        for (int mi = 0; mi < 4; mi++) af[mi]  = *(const bf16x8*)(ArA + mi * 512);
#pragma unroll
        for (int ni = 0; ni < 4; ni++) bfr[ni] = *(const bf16x8*)(BrB + ni * 512);
#pragma unroll
        for (int mi = 0; mi < 4; mi++)
#pragma unroll
            for (int ni = 0; ni < 4; ni++)
                acc[mi][ni] = __builtin_amdgcn_mfma_f32_16x16x32_bf16(
                    af[mi], bfr[ni], acc[mi][ni], 0, 0, 0);
    }

    const int cr = (lane >> 4) << 2;
    const int cc = lane & 15;
#pragma unroll
    for (int mi = 0; mi < 4; mi++) {
#pragma unroll
        for (int r = 0; r < 4; r++) {
            long grow = row0 + wm * 64 + mi * 16 + cr + r;
#pragma unroll
            for (int ni = 0; ni < 4; ni++) {
                long gcol = col0 + wn * 64 + ni * 16 + cc;
                float v = acc[mi][ni][r];
                if (OUTMODE == 0) ((float*)Cp)[grow * N + gcol] = v;
                else              ((u16*)Cp)[grow * N + gcol] = f2b(v);
            }
        }
    }
}

// ---------------------------------------------------------------------------
// Routed-expert bf16 MFMA GEMM (gathered rows, scaled atomicAdd epilogue)
// ---------------------------------------------------------------------------
__global__ __launch_bounds__(256) void routed_gemm(const u16* __restrict__ Hh,
                                                   const u16* __restrict__ W2T,
                                                   const int* __restrict__ list,
                                                   const float* __restrict__ wlist,
                                                   const int* __restrict__ bases,
                                                   const int* __restrict__ counts,
                                                   float* __restrict__ Cout) {
    const int e    = blockIdx.y >> 5;
    const int tile = blockIdx.y & 31;
    const int cnt  = counts[e];
    if (tile * 128 >= cnt) return;
    const int base = bases[e];

    __shared__ u16 As[128 * 32];
    __shared__ u16 Bs[128 * 32];
    __shared__ int   toks[128];
    __shared__ float wrow[128];

    const int tid = threadIdx.x;
    if (tid < 128) {
        int ridx = tile * 128 + tid;
        if (ridx < cnt) { toks[tid] = list[base + ridx]; wrow[tid] = wlist[base + ridx]; }
        else            { toks[tid] = -1;                wrow[tid] = 0.f; }
    }
    __syncthreads();

    const int lane = tid & 63;
    const int wv   = tid >> 6;
    const int wm   = wv >> 1, wn = wv & 1;
    const long col0 = (long)blockIdx.x * 128;

    f32x4 acc[4][4];
#pragma unroll
    for (int i = 0; i < 4; i++)
#pragma unroll
        for (int j = 0; j < 4; j++) acc[i][j] = (f32x4){0.f, 0.f, 0.f, 0.f};

    const int sr = tid >> 2;
    const int sc = (tid & 3) << 3;
    const int t1 = toks[sr], t2 = toks[sr + 64];
    const u16* Ag  = Hh + (long)(t1 < 0 ? 0 : t1) * HID_ + sc;
    const u16* Ag2 = Hh + (long)(t2 < 0 ? 0 : t2) * HID_ + sc;
    const u16* Bg  = W2T + (long)e * D_ * HID_ + (col0 + sr) * (long)HID_ + sc;
    const u16* Bg2 = Bg + 64 * (long)HID_;
    u16* lA  = As + tid * 8;
    u16* lA2 = As + 2048 + tid * 8;
    u16* lB  = Bs + tid * 8;
    u16* lB2 = Bs + 2048 + tid * 8;

    const int fl = lane & 15;
    const int fk = (lane >> 4) << 3;
    const u16* ArA = As + (wm * 64 + fl) * 32 + fk;
    const u16* BrB = Bs + (wn * 64 + fl) * 32 + fk;

    for (int k0 = 0; k0 < HID_; k0 += 32) {
        __syncthreads();
        g2l16(Ag + k0, lA);
        g2l16(Ag2 + k0, lA2);
        g2l16(Bg + k0, lB);
        g2l16(Bg2 + k0, lB2);
        __syncthreads();
        bf16x8 af[4], bfr[4];
#pragma unroll
        for (int mi = 0; mi < 4; mi++) af[mi]  = *(const bf16x8*)(ArA + mi * 512);
#pragma unroll
        for (int ni = 0; ni < 4; ni++) bfr[ni] = *(const bf16x8*)(BrB + ni * 512);
#pragma unroll
        for (int mi = 0; mi < 4; mi++)
#pragma unroll
            for (int ni = 0; ni < 4; ni++)
                acc[mi][ni] = __builtin_amdgcn_mfma_f32_16x16x32_bf16(
                    af[mi], bfr[ni], acc[mi][ni], 0, 0, 0);
    }

    const int cr = (lane >> 4) << 2;
    const int cc = lane & 15;
#pragma unroll
    for (int mi = 0; mi < 4; mi++) {
#pragma unroll
        for (int r = 0; r < 4; r++) {
            int rr = wm * 64 + mi * 16 + cr + r;
            int tk = toks[rr];
            if (tk < 0) continue;
            float wvw = wrow[rr];
            float* crow = Cout + (long)tk * D_ + col0 + wn * 64;
#pragma unroll
            for (int ni = 0; ni < 4; ni++)
                atomicAdd(crow + ni * 16 + cc, acc[mi][ni][r] * wvw);
        }
    }
}

// ---------------------------------------------------------------------------
// RoPE in place on bf16 (S,D) buffer.
// ---------------------------------------------------------------------------
__global__ __launch_bounds__(256) void rope_kernel(u16* __restrict__ x) {
    long p = (long)blockIdx.x * 256 + threadIdx.x;
    int s = (int)(p / (D_ / 2));
    int r = (int)(p % (D_ / 2));
    int t = s & (T_ - 1);
    int d = r * 2;
    int i = (d & (DH_ - 1)) >> 1;
    float ang = (float)t * powf(10000.f, -(float)i / 32.f);
    float sn, cs;
    sincosf(ang, &sn, &cs);
    u16* px = x + (long)s * D_ + d;
    float x1 = b2f(px[0]), x2 = b2f(px[1]);
    px[0] = f2b(x1 * cs - x2 * sn);
    px[1] = f2b(x1 * sn + x2 * cs);
}

// ---------------------------------------------------------------------------
// MFMA flash attention. grid (T/64, B*H), 256 thr = 4 waves, each wave owns
// 16 q-rows. K tile (64key x 64d) and Vt tile (64d x 64key) staged in LDS via
// global_load_lds with XOR-swizzled 16B groups (group ^= row&7) so b128 frag
// reads hit all 32 banks. P (16x64 per wave) round-trips LDS in same swizzle.
// ---------------------------------------------------------------------------
__global__ __launch_bounds__(256, 4) void attn_kernel(const u16* __restrict__ qb,
                                                      const u16* __restrict__ kb,
                                                      const u16* __restrict__ vtg,
                                                      u16* __restrict__ sab) {
    __shared__ u16 Ks[64 * 64];
    __shared__ u16 Vs[64 * 64];
    __shared__ u16 Ps[4][16 * 64];
    const int tid  = threadIdx.x;
    const int lane = tid & 63;
    const int w    = tid >> 6;
    const int bh = blockIdx.y;
    const int b  = bh >> 4, h = bh & 15;
    const long tok0 = (long)b * T_ + blockIdx.x * 64;
    const int fl = lane & 15;
    const int fq = lane >> 4;

    // Q fragments straight from global (A-operand layout)
    bf16x8 qf0, qf1;
    {
        const u16* qp = qb + (tok0 + w * 16 + fl) * D_ + h * 64 + fq * 8;
        qf0 = *(const bf16x8*)qp;
        qf1 = *(const bf16x8*)(qp + 32);
    }

    // staging slots: two passes of 256 over 512 slots; slot i -> row i>>3, grp i&7
    const int r0 = tid >> 3,          gg0 = tid & 7;
    const int i1 = tid + 256;
    const int r1 = i1 >> 3,           gg1 = i1 & 7;
    const u16* kb0 = kb + ((long)b * T_) * D_ + h * 64;
    const u16* vb0 = vtg + ((long)bh * 64) * T_;

    float m_[4], l_[4];
    f32x4 oacc[4];
#pragma unroll
    for (int i = 0; i < 4; i++) {
        m_[i] = -1e30f; l_[i] = 0.f;
        oacc[i] = (f32x4){0.f, 0.f, 0.f, 0.f};
    }

    for (int kt = 0; kt < T_ / 64; kt++) {
        __syncthreads();
        g2l16(kb0 + (long)(kt * 64 + r0) * D_ + (gg0 ^ (r0 & 7)) * 8, Ks + tid * 8);
        g2l16(kb0 + (long)(kt * 64 + r1) * D_ + (gg1 ^ (r1 & 7)) * 8, Ks + i1 * 8);
        g2l16(vb0 + (long)r0 * T_ + kt * 64 + (gg0 ^ (r0 & 7)) * 8, Vs + tid * 8);
        g2l16(vb0 + (long)r1 * T_ + kt * 64 + (gg1 ^ (r1 & 7)) * 8, Vs + i1 * 8);
        __syncthreads();

        // S = Q K^T  (16 q-rows x 64 k-cols per wave)
        f32x4 sacc[4];
#pragma unroll
        for (int ni = 0; ni < 4; ni++) sacc[ni] = (f32x4){0.f, 0.f, 0.f, 0.f};
#pragma unroll
        for (int ks = 0; ks < 2; ks++) {
            bf16x8 qq = ks ? qf1 : qf0;
#pragma unroll
            for (int ni = 0; ni < 4; ni++) {
                bf16x8 kf = *(const bf16x8*)(Ks + (ni * 16 + fl) * 64 +
                                             (((ks * 4 + fq) ^ (fl & 7)) << 3));
                sacc[ni] = __builtin_amdgcn_mfma_f32_16x16x32_bf16(qq, kf, sacc[ni], 0, 0, 0);
            }
        }

        // online softmax; lane's C rows = fq*4+r
        float rmax[4];
#pragma unroll
        for (int r = 0; r < 4; r++)
            rmax[r] = fmaxf(fmaxf(sacc[0][r], sacc[1][r]),
                            fmaxf(sacc[2][r], sacc[3][r])) * 0.125f;
#pragma unroll
        for (int off = 1; off < 16; off <<= 1)
#pragma unroll
            for (int r = 0; r < 4; r++) rmax[r] = fmaxf(rmax[r], __shfl_xor(rmax[r], off));
        float alpha[4], psum[4];
#pragma unroll
        for (int r = 0; r < 4; r++) {
            float nm = fmaxf(m_[r], rmax[r]);
            alpha[r] = __expf(m_[r] - nm);
            m_[r] = nm;
            psum[r] = 0.f;
        }
        u16* pst = Ps[w];
#pragma unroll
        for (int ni = 0; ni < 4; ni++) {
            int colg = ni * 2 + (fl >> 3);
            int cl   = fl & 7;
#pragma unroll
            for (int r = 0; r < 4; r++) {
                int row = fq * 4 + r;
                float p = __expf(sacc[ni][r] * 0.125f - m_[r]);
                psum[r] += p;
                pst[row * 64 + ((colg ^ (row & 7)) << 3) + cl] = f2b(p);
            }
        }
#pragma unroll
        for (int off = 1; off < 16; off <<= 1)
#pragma unroll
            for (int r = 0; r < 4; r++) psum[r] += __shfl_xor(psum[r], off);
#pragma unroll
        for (int r = 0; r < 4; r++) l_[r] = l_[r] * alpha[r] + psum[r];
#pragma unroll
        for (int ni = 0; ni < 4; ni++)
#pragma unroll
            for (int r = 0; r < 4; r++) oacc[ni][r] *= alpha[r];

        // O += P V   (P strip is wave-private; lgkmcnt ordering within wave)
#pragma unroll
        for (int ks = 0; ks < 2; ks++) {
            bf16x8 pf = *(const bf16x8*)(pst + fl * 64 +
                                         (((ks * 4 + fq) ^ (fl & 7)) << 3));
#pragma unroll
            for (int ni = 0; ni < 4; ni++) {
                bf16x8 vf = *(const bf16x8*)(Vs + (ni * 16 + fl) * 64 +
                                             (((ks * 4 + fq) ^ (fl & 7)) << 3));
                oacc[ni] = __builtin_amdgcn_mfma_f32_16x16x32_bf16(pf, vf, oacc[ni], 0, 0, 0);
            }
        }
    }

#pragma unroll
    for (int r = 0; r < 4; r++) {
        float inv = 1.f / l_[r];
        u16* op = sab + (tok0 + w * 16 + fq * 4 + r) * D_ + h * 64 + fl;
#pragma unroll
        for (int ni = 0; ni < 4; ni++) op[ni * 16] = f2b(oacc[ni][r] * inv);
    }
}

// ---------------------------------------------------------------------------
// Residual add + RMSNorm. BF=1 additionally writes bf16 copy.
// ---------------------------------------------------------------------------
template<int BF>
__global__ __launch_bounds__(256) void rmsnorm_res(const float* __restrict__ a,
                                                   const float* __restrict__ b,
                                                   const float* __restrict__ w,
                                                   float* __restrict__ outf,
                                                   u16* __restrict__ outb) {
    const int s = blockIdx.x;
    const float* ar = a + (long)s * D_;
    const float* br = b + (long)s * D_;
    float y[4];
    float ss = 0.f;
#pragma unroll
    for (int kx = 0; kx < 4; kx++) {
        int j = threadIdx.x + kx * 256;
        y[kx] = ar[j] + br[j];
        ss += y[kx] * y[kx];
    }
    __shared__ float red[4];
#pragma unroll
    for (int off = 32; off > 0; off >>= 1) ss += __shfl_down(ss, off);
    int lane = threadIdx.x & 63, wv = threadIdx.x >> 6;
    if (lane == 0) red[wv] = ss;
    __syncthreads();
    float tot = red[0] + red[1] + red[2] + red[3];
    float scl = rsqrtf(tot / (float)D_ + EPS_);
    float* orow = outf + (long)s * D_;
#pragma unroll
    for (int kx = 0; kx < 4; kx++) {
        int j = threadIdx.x + kx * 256;
        float v = y[kx] * scl * w[j];
        orow[j] = v;
        if (BF) outb[(long)s * D_ + j] = f2b(v);
    }
}

// SwiGLU: bf16 mid (S, 2*HID) -> bf16 h (S, HID)
__global__ __launch_bounds__(256) void swiglu_kernel(const u16* __restrict__ mid,
                                                     u16* __restrict__ h) {
    long idx = (long)blockIdx.x * 256 + threadIdx.x;
    long srow = idx / HID_;
    int j = (int)(idx % HID_);
    float a  = b2f(mid[srow * (2 * HID_) + j]);
    float bb = b2f(mid[srow * (2 * HID_) + HID_ + j]);
    float sig = 1.f / (1.f + __expf(-a));
    h[idx] = f2b(a * sig * bb);
}

// ---------------------------------------------------------------------------
// Gating (fp32): one wave per token.
// ---------------------------------------------------------------------------
__global__ __launch_bounds__(256) void gate_kernel(const float* __restrict__ x,
                                                   const float* __restrict__ Wg,
                                                   const float* __restrict__ We,
                                                   const float* __restrict__ gb,
                                                   const float* __restrict__ eb,
                                                   int* __restrict__ tok_e,
                                                   float* __restrict__ tok_w,
                                                   int* __restrict__ counts) {
    const int wave = threadIdx.x >> 6;
    const int lane = threadIdx.x & 63;
    const int s = blockIdx.x * 4 + wave;
    const float* xr = x + (long)s * D_;
    float g0 = 0.f, g1 = 0.f;
    float ee[8];
#pragma unroll
    for (int e = 0; e < 8; e++) ee[e] = 0.f;
    for (int j = lane; j < D_; j += 64) {
        float xv = xr[j];
        g0 += xv * Wg[j * 2 + 0];
        g1 += xv * Wg[j * 2 + 1];
#pragma unroll
        for (int e = 0; e < 8; e++) ee[e] += xv * We[j * 8 + e];
    }
#pragma unroll
    for (int off = 32; off > 0; off >>= 1) {
        g0 += __shfl_down(g0, off);
        g1 += __shfl_down(g1, off);
#pragma unroll
        for (int e = 0; e < 8; e++) ee[e] += __shfl_down(ee[e], off);
    }
    if (lane == 0) {
        g0 += gb[0];
        g1 += gb[1];
        int gidx = (g1 > g0) ? 1 : 0;
        float gm = fmaxf(g0, g1);
        float p0 = expf(g0 - gm), p1 = expf(g1 - gm);
        float gprob = (gidx ? p1 : p0) / (p0 + p1);
        int base = gidx * 4;
        float pe[4];
        float em = -1e30f;
#pragma unroll
        for (int i = 0; i < 4; i++) {
            pe[i] = ee[base + i] + eb[base + i];
            em = fmaxf(em, pe[i]);
        }
        float sum = 0.f;
#pragma unroll
        for (int i = 0; i < 4; i++) { pe[i] = expf(pe[i] - em); sum += pe[i]; }
        float inv = gprob / sum;
#pragma unroll
        for (int i = 0; i < 4; i++) pe[i] *= inv;
        int i1 = 0;
        for (int i = 1; i < 4; i++) if (pe[i] > pe[i1]) i1 = i;
        int i2 = -1;
        for (int i = 0; i < 4; i++) {
            if (i == i1) continue;
            if (i2 < 0 || pe[i] > pe[i2]) i2 = i;
        }
        tok_e[s * 2 + 0] = base + i1;
        tok_e[s * 2 + 1] = base + i2;
        tok_w[s * 2 + 0] = pe[i1];
        tok_w[s * 2 + 1] = pe[i2];
        atomicAdd(&counts[base + i1], 1);
        atomicAdd(&counts[base + i2], 1);
    }
}

__global__ void zero_counts(int* counts) {
    if (threadIdx.x < E_) counts[threadIdx.x] = 0;
}

__global__ void scan_kernel(const int* __restrict__ counts,
                            int* __restrict__ bases,
                            int* __restrict__ cursors) {
    if (threadIdx.x == 0 && blockIdx.x == 0) {
        int acc = 0;
        for (int e = 0; e < E_; e++) {
            bases[e] = acc; cursors[e] = acc; acc += counts[e];
        }
    }
}

__global__ __launch_bounds__(256) void scatter_kernel(const int* __restrict__ tok_e,
                                                      const float* __restrict__ tok_w,
                                                      int* __restrict__ cursors,
                                                      int* __restrict__ list,
                                                      float* __restrict__ wlist) {
    int s = blockIdx.x * 256 + threadIdx.x;
    if (s >= S_) return;
#pragma unroll
    for (int t = 0; t < 2; t++) {
        int e = tok_e[s * 2 + t];
        int pos = atomicAdd(&cursors[e], 1);
        list[pos] = s;
        wlist[pos] = tok_w[s * 2 + t];
    }
}

// ---------------------------------------------------------------------------
extern "C" void kernel_launch(void* const* d_in, const int* in_sizes, int n_in,
                              void* d_out, int out_size, void* d_ws, size_t ws_size,
                              hipStream_t stream) {
    const float* src  = (const float*)d_in[0];
    const float* Wq   = (const float*)d_in[1];
    const float* Wk_c = (const float*)d_in[2];
    const float* Wv_c = (const float*)d_in[3];
    const float* Wk   = (const float*)d_in[4];
    const float* Wv   = (const float*)d_in[5];
    const float* Wo   = (const float*)d_in[6];
    const float* Wsin = (const float*)d_in[7];
    const float* Wsout= (const float*)d_in[8];
    const float* W1   = (const float*)d_in[9];
    const float* W2   = (const float*)d_in[10];
    const float* Wg   = (const float*)d_in[11];
    const float* We   = (const float*)d_in[12];
    const float* gb   = (const float*)d_in[13];
    const float* eb   = (const float*)d_in[14];
    const float* n1w  = (const float*)d_in[15];
    const float* n2w  = (const float*)d_in[16];
    float* out = (float*)d_out;

    const size_t MB = 1u << 20;
    char* w8 = (char*)d_ws;
    u16*  qb    = (u16*)(w8);
    u16*  kbuf  = (u16*)(w8 + 8 * MB);
    u16*  vbuf  = (u16*)(w8 + 16 * MB);
    u16*  kcb   = (u16*)(w8 + 24 * MB);
    u16*  vcb   = (u16*)(w8 + 26 * MB);
    u16*  srcb  = (u16*)(w8 + 28 * MB);
    float* oproj= (float*)(w8);
    u16*  midb  = (u16*)(w8);
    u16*  w2t   = (u16*)(w8);
    u16*  sab   = (u16*)(w8 + 36 * MB);
    float* x1   = (float*)(w8 + 44 * MB);
    float* ffn  = (float*)(w8 + 60 * MB);
    u16*  x1b   = (u16*)(w8 + 76 * MB);
    u16*  hbuf  = (u16*)(w8 + 84 * MB);
    u16*  WqT   = (u16*)(w8 + 100 * MB);
    u16*  WkcT  = (u16*)(w8 + 102 * MB);
    u16*  WvcT  = (u16*)(w8 + 102 * MB + 512 * 1024);
    u16*  WkT   = (u16*)(w8 + 103 * MB);
    u16*  WvT   = (u16*)(w8 + 103 * MB + 512 * 1024);
    u16*  WoT   = (u16*)(w8 + 104 * MB);
    u16*  WsinT = (u16*)(w8 + 106 * MB);
    u16*  WsoutT= (u16*)(w8 + 114 * MB);
    u16*  W1T   = (u16*)(w8 + 118 * MB);
    float* tokw = (float*)(w8 + 126 * MB);
    float* wlist = tokw + 2 * S_;
    int* toke   = (int*)(wlist + 2 * S_);
    int* list   = toke + 2 * S_;
    int* counts = list + 2 * S_;
    int* bases  = counts + E_;
    int* cursors= bases + E_;
    u16*  vtg   = (u16*)(w8 + 128 * MB);   // [bh][64][T] bf16 = 8 MB

    dim3 blk(256);

    zero_counts<<<dim3(1), dim3(64), 0, stream>>>(counts);

    // Weight conversions (fp32 (K,N) -> bf16 (N,K))
    conv_t<<<dim3(32, 32), blk, 0, stream>>>(Wq,    WqT,    1024, 1024, 0, 0);
    conv_t<<<dim3(8, 32),  blk, 0, stream>>>(Wk_c,  WkcT,   1024, 256,  0, 0);
    conv_t<<<dim3(8, 32),  blk, 0, stream>>>(Wv_c,  WvcT,   1024, 256,  0, 0);
    conv_t<<<dim3(32, 8),  blk, 0, stream>>>(Wk,    WkT,    256,  1024, 0, 0);
    conv_t<<<dim3(32, 8),  blk, 0, stream>>>(Wv,    WvT,    256,  1024, 0, 0);
    conv_t<<<dim3(32, 32), blk, 0, stream>>>(Wo,    WoT,    1024, 1024, 0, 0);
    conv_t<<<dim3(128, 32),blk, 0, stream>>>(Wsin,  WsinT,  1024, 4096, 0, 0);
    conv_t<<<dim3(32, 64), blk, 0, stream>>>(Wsout, WsoutT, 2048, 1024, 0, 0);
    conv_t<<<dim3(128, 32),blk, 0, stream>>>(W1,    W1T,    1024, 4096, 0, 0);
    convert_bf16<<<dim3(S_ * D_ / 4 / 256), blk, 0, stream>>>(src, srcb, S_ * D_ / 4);

    // QKV projections (bf16 MFMA)
    gemm_bf16<1><<<dim3(8, 32), blk, 0, stream>>>(srcb, WqT,  qb,   1024, 1024);
    gemm_bf16<1><<<dim3(2, 32), blk, 0, stream>>>(srcb, WkcT, kcb,  256,  1024);
    gemm_bf16<1><<<dim3(2, 32), blk, 0, stream>>>(srcb, WvcT, vcb,  256,  1024);
    gemm_bf16<1><<<dim3(8, 32), blk, 0, stream>>>(kcb,  WkT,  kbuf, 1024, 256);
    gemm_bf16<1><<<dim3(8, 32), blk, 0, stream>>>(vcb,  WvT,  vbuf, 1024, 256);

    rope_kernel<<<dim3(S_ * (D_ / 2) / 256), blk, 0, stream>>>(qb);
    rope_kernel<<<dim3(S_ * (D_ / 2) / 256), blk, 0, stream>>>(kbuf);

    vt_conv<<<dim3(T_ / 32, 2, B_ * H_), blk, 0, stream>>>(vbuf, vtg);
    attn_kernel<<<dim3(T_ / 64, B_ * H_), blk, 0, stream>>>(qb, kbuf, vtg, sab);

    gemm_bf16<0><<<dim3(8, 32), blk, 0, stream>>>(sab, WoT, oproj, 1024, 1024);
    rmsnorm_res<1><<<dim3(S_), blk, 0, stream>>>(src, oproj, n1w, x1, x1b);

    // Shared FFN
    gemm_bf16<1><<<dim3(32, 32), blk, 0, stream>>>(x1b, WsinT, midb, 4096, 1024);
    swiglu_kernel<<<dim3(S_ * HID_ / 256), blk, 0, stream>>>(midb, hbuf);
    gemm_bf16<0><<<dim3(8, 32), blk, 0, stream>>>(hbuf, WsoutT, ffn, 1024, 2048);

    // Gating
    gate_kernel<<<dim3(S_ / 4), blk, 0, stream>>>(x1, Wg, We, gb, eb, toke, tokw, counts);
    scan_kernel<<<dim3(1), dim3(1), 0, stream>>>(counts, bases, cursors);
    scatter_kernel<<<dim3(S_ / 256), blk, 0, stream>>>(toke, tokw, cursors, list, wlist);

    // Routed experts
    gemm_bf16<1><<<dim3(32, 32), blk, 0, stream>>>(x1b, W1T, midb, 4096, 1024);
    swiglu_kernel<<<dim3(S_ * HID_ / 256), blk, 0, stream>>>(midb, hbuf);
    conv_t<<<dim3(32, 64, 8), blk, 0, stream>>>(W2, w2t, 2048, 1024,
                                                (long)HID_ * D_, (long)D_ * HID_);
    routed_gemm<<<dim3(8, E_ * 32), blk, 0, stream>>>(hbuf, w2t, list, wlist,
                                                      bases, counts, ffn);

    rmsnorm_res<0><<<dim3(S_), blk, 0, stream>>>(x1, ffn, n2w, out, (u16*)nullptr);
}

// Round 5
// 813.540 us; speedup vs baseline: 5.3706x; 1.0709x over previous
//
#include <hip/hip_runtime.h>
#include <math.h>

#define D_    1024
#define H_    16
#define DH_   64
#define DC_   256
#define HID_  2048
#define E_    8
#define B_    2
#define T_    2048
#define S_    4096
#define EPS_  1e-6f
#define QKVW_ 3072   // fused qkv row width

typedef unsigned short u16;
typedef short bf16x8 __attribute__((ext_vector_type(8)));
typedef float f32x4 __attribute__((ext_vector_type(4)));

__device__ __forceinline__ float b2f(u16 u) {
    return __uint_as_float(((unsigned int)u) << 16);
}
__device__ __forceinline__ u16 f2b(float f) {
    unsigned int u = __float_as_uint(f);
    u += 0x7FFF + ((u >> 16) & 1);
    return (u16)(u >> 16);
}
__device__ __forceinline__ void g2l16(const u16* g, u16* l) {
    __builtin_amdgcn_global_load_lds(
        (const __attribute__((address_space(1))) void*)g,
        (__attribute__((address_space(3))) void*)l, 16, 0, 0);
}

// ---------------------------------------------------------------------------
// Transpose + fp32->bf16: in (K,N) fp32 -> out (N,K) bf16.
// perm=1: swiglu column interleave — output row r reads source col:
//   t64=r/64, i=r%64; i<32 -> t64*32+i (gate), else N/2 + t64*32 + (i-32) (up)
// ---------------------------------------------------------------------------
__global__ __launch_bounds__(256) void conv_t(const float* __restrict__ in,
                                              u16* __restrict__ out,
                                              int K, int N,
                                              long inZ, long outZ, int perm) {
    in  += (long)blockIdx.z * inZ;
    out += (long)blockIdx.z * outZ;
    __shared__ float t[32][33];
    const int n0 = blockIdx.x * 32, k0 = blockIdx.y * 32;
    int src_n0 = n0;
    if (perm) {
        int t64 = n0 >> 6;
        src_n0 = ((n0 & 63) == 0) ? t64 * 32 : (N / 2 + t64 * 32);
    }
    const int tx = threadIdx.x & 31, ty = threadIdx.x >> 5;
#pragma unroll
    for (int i = 0; i < 4; i++)
        t[ty + 8 * i][tx] = in[(long)(k0 + ty + 8 * i) * N + src_n0 + tx];
    __syncthreads();
#pragma unroll
    for (int i = 0; i < 4; i++)
        out[(long)(n0 + ty + 8 * i) * K + k0 + tx] = f2b(t[tx][ty + 8 * i]);
}

// bf16 transpose V rows of fused qkv (stride QKVW_) per-head -> Vt [bh][64][T]
__global__ __launch_bounds__(256) void vt_conv(const u16* __restrict__ qkv,
                                               u16* __restrict__ vt) {
    __shared__ u16 t[32][34];
    const int bh = blockIdx.z;
    const int b = bh >> 4, h = bh & 15;
    const int t0 = blockIdx.x * 32, d0 = blockIdx.y * 32;
    const int tx = threadIdx.x & 31, ty = threadIdx.x >> 5;
#pragma unroll
    for (int i = 0; i < 4; i++)
        t[ty + 8 * i][tx] =
            qkv[((long)b * T_ + t0 + ty + 8 * i) * QKVW_ + 2048 + h * 64 + d0 + tx];
    __syncthreads();
#pragma unroll
    for (int i = 0; i < 4; i++)
        vt[((long)bh * 64 + d0 + ty + 8 * i) * T_ + t0 + tx] = t[tx][ty + 8 * i];
}

// Elementwise fp32 -> bf16
__global__ __launch_bounds__(256) void convert_bf16(const float* __restrict__ in,
                                                    u16* __restrict__ out, int n4) {
    int i = blockIdx.x * 256 + threadIdx.x;
    if (i >= n4) return;
    float4 f = ((const float4*)in)[i];
    ushort4 o;
    o.x = f2b(f.x); o.y = f2b(f.y); o.z = f2b(f.z); o.w = f2b(f.w);
    ((ushort4*)out)[i] = o;
}

// ---------------------------------------------------------------------------
// bf16 MFMA GEMM: C(M,N) = A(M,K) @ Bt(N,K)^T. 128x128, BK=32, 4 waves.
// OUTMODE 0: fp32, C[grow*ldo+gcol]
// OUTMODE 1: bf16, C[grow*ldo+gcol]
// OUTMODE 2: bf16 transposed, C[gcol*ldo+grow]        (ldo = M)
// OUTMODE 3: swiglu epilogue, bf16 h[grow*ldo + bx*64+wn*32+ni*16+cc] (ldo=N/2)
// ---------------------------------------------------------------------------
template<int OUTMODE>
__global__ __launch_bounds__(256) void gemm_bf16(const u16* __restrict__ A,
                                                 const u16* __restrict__ Bt,
                                                 void* __restrict__ Cp,
                                                 int N, int K, int ldo) {
    __shared__ u16 As[128 * 32];
    __shared__ u16 Bs[128 * 32];
    const int tid  = threadIdx.x;
    const int lane = tid & 63;
    const int wv   = tid >> 6;
    const int wm   = wv >> 1, wn = wv & 1;
    const long row0 = (long)blockIdx.y * 128;
    const long col0 = (long)blockIdx.x * 128;

    f32x4 acc[4][4];
#pragma unroll
    for (int i = 0; i < 4; i++)
#pragma unroll
        for (int j = 0; j < 4; j++) acc[i][j] = (f32x4){0.f, 0.f, 0.f, 0.f};

    const int sr = tid >> 2;
    const int sc = (tid & 3) << 3;
    const u16* Ag  = A  + (row0 + sr) * (long)K + sc;
    const u16* Ag2 = Ag + 64 * (long)K;
    const u16* Bg  = Bt + (col0 + sr) * (long)K + sc;
    const u16* Bg2 = Bg + 64 * (long)K;
    u16* lA  = As + tid * 8;
    u16* lA2 = As + 2048 + tid * 8;
    u16* lB  = Bs + tid * 8;
    u16* lB2 = Bs + 2048 + tid * 8;

    const int fl = lane & 15;
    const int fk = (lane >> 4) << 3;
    const u16* ArA = As + (wm * 64 + fl) * 32 + fk;
    const u16* BrB = Bs + (wn * 64 + fl) * 32 + fk;

    for (int k0 = 0; k0 < K; k0 += 32) {
        __syncthreads();
        g2l16(Ag + k0, lA);
        g2l16(Ag2 + k0, lA2);
        g2l16(Bg + k0, lB);
        g2l16(Bg2 + k0, lB2);
        __syncthreads();
        bf16x8 af[4], bfr[4];
#pragma unroll
        for (int mi = 0; mi < 4; mi++) af[mi]  = *(const bf16x8*)(ArA + mi * 512);
#pragma unroll
        for (int ni = 0; ni < 4; ni++) bfr[ni] = *(const bf16x8*)(BrB + ni * 512);
#pragma unroll
        for (int mi = 0; mi < 4; mi++)
#pragma unroll
            for (int ni = 0; ni < 4; ni++)
                acc[mi][ni] = __builtin_amdgcn_mfma_f32_16x16x32_bf16(
                    af[mi], bfr[ni], acc[mi][ni], 0, 0, 0);
    }

    const int cr = (lane >> 4) << 2;
    const int cc = lane & 15;
#pragma unroll
    for (int mi = 0; mi < 4; mi++) {
#pragma unroll
        for (int r = 0; r < 4; r++) {
            long grow = row0 + wm * 64 + mi * 16 + cr + r;
            if (OUTMODE == 3) {
                u16* hrow = (u16*)Cp + grow * ldo + blockIdx.x * 64 + wn * 32;
#pragma unroll
                for (int ni = 0; ni < 2; ni++) {
                    float a = acc[mi][ni][r], b = acc[mi][ni + 2][r];
                    float sig = 1.f / (1.f + __expf(-a));
                    hrow[ni * 16 + cc] = f2b(a * sig * b);
                }
            } else {
#pragma unroll
                for (int ni = 0; ni < 4; ni++) {
                    long gcol = col0 + wn * 64 + ni * 16 + cc;
                    float v = acc[mi][ni][r];
                    if (OUTMODE == 0)      ((float*)Cp)[grow * ldo + gcol] = v;
                    else if (OUTMODE == 1) ((u16*)Cp)[grow * ldo + gcol] = f2b(v);
                    else                   ((u16*)Cp)[gcol * ldo + grow] = f2b(v);
                }
            }
        }
    }
}

// ---------------------------------------------------------------------------
// Routed-expert bf16 MFMA GEMM (gathered rows, scaled atomicAdd epilogue)
// ---------------------------------------------------------------------------
__global__ __launch_bounds__(256) void routed_gemm(const u16* __restrict__ Hh,
                                                   const u16* __restrict__ W2T,
                                                   const int* __restrict__ list,
                                                   const float* __restrict__ wlist,
                                                   const int* __restrict__ bases,
                                                   const int* __restrict__ counts,
                                                   float* __restrict__ Cout) {
    const int e    = blockIdx.y >> 5;
    const int tile = blockIdx.y & 31;
    const int cnt  = counts[e];
    if (tile * 128 >= cnt) return;
    const int base = bases[e];

    __shared__ u16 As[128 * 32];
    __shared__ u16 Bs[128 * 32];
    __shared__ int   toks[128];
    __shared__ float wrow[128];

    const int tid = threadIdx.x;
    if (tid < 128) {
        int ridx = tile * 128 + tid;
        if (ridx < cnt) { toks[tid] = list[base + ridx]; wrow[tid] = wlist[base + ridx]; }
        else            { toks[tid] = -1;                wrow[tid] = 0.f; }
    }
    __syncthreads();

    const int lane = tid & 63;
    const int wv   = tid >> 6;
    const int wm   = wv >> 1, wn = wv & 1;
    const long col0 = (long)blockIdx.x * 128;

    f32x4 acc[4][4];
#pragma unroll
    for (int i = 0; i < 4; i++)
#pragma unroll
        for (int j = 0; j < 4; j++) acc[i][j] = (f32x4){0.f, 0.f, 0.f, 0.f};

    const int sr = tid >> 2;
    const int sc = (tid & 3) << 3;
    const int t1 = toks[sr], t2 = toks[sr + 64];
    const u16* Ag  = Hh + (long)(t1 < 0 ? 0 : t1) * HID_ + sc;
    const u16* Ag2 = Hh + (long)(t2 < 0 ? 0 : t2) * HID_ + sc;
    const u16* Bg  = W2T + (long)e * D_ * HID_ + (col0 + sr) * (long)HID_ + sc;
    const u16* Bg2 = Bg + 64 * (long)HID_;
    u16* lA  = As + tid * 8;
    u16* lA2 = As + 2048 + tid * 8;
    u16* lB  = Bs + tid * 8;
    u16* lB2 = Bs + 2048 + tid * 8;

    const int fl = lane & 15;
    const int fk = (lane >> 4) << 3;
    const u16* ArA = As + (wm * 64 + fl) * 32 + fk;
    const u16* BrB = Bs + (wn * 64 + fl) * 32 + fk;

    for (int k0 = 0; k0 < HID_; k0 += 32) {
        __syncthreads();
        g2l16(Ag + k0, lA);
        g2l16(Ag2 + k0, lA2);
        g2l16(Bg + k0, lB);
        g2l16(Bg2 + k0, lB2);
        __syncthreads();
        bf16x8 af[4], bfr[4];
#pragma unroll
        for (int mi = 0; mi < 4; mi++) af[mi]  = *(const bf16x8*)(ArA + mi * 512);
#pragma unroll
        for (int ni = 0; ni < 4; ni++) bfr[ni] = *(const bf16x8*)(BrB + ni * 512);
#pragma unroll
        for (int mi = 0; mi < 4; mi++)
#pragma unroll
            for (int ni = 0; ni < 4; ni++)
                acc[mi][ni] = __builtin_amdgcn_mfma_f32_16x16x32_bf16(
                    af[mi], bfr[ni], acc[mi][ni], 0, 0, 0);
    }

    const int cr = (lane >> 4) << 2;
    const int cc = lane & 15;
#pragma unroll
    for (int mi = 0; mi < 4; mi++) {
#pragma unroll
        for (int r = 0; r < 4; r++) {
            int rr = wm * 64 + mi * 16 + cr + r;
            int tk = toks[rr];
            if (tk < 0) continue;
            float wvw = wrow[rr];
            float* crow = Cout + (long)tk * D_ + col0 + wn * 64;
#pragma unroll
            for (int ni = 0; ni < 4; ni++)
                atomicAdd(crow + ni * 16 + cc, acc[mi][ni][r] * wvw);
        }
    }
}

// ---------------------------------------------------------------------------
// RoPE in place on q,k columns (0..2047) of fused qkv (row stride QKVW_).
// ---------------------------------------------------------------------------
__global__ __launch_bounds__(256) void rope_kernel(u16* __restrict__ qkv) {
    long p = (long)blockIdx.x * 256 + threadIdx.x;   // S_*2048/2 pairs
    int s = (int)(p >> 10);
    int r = (int)(p & 1023);
    int t = s & (T_ - 1);
    int d = r * 2;
    int i = (d & (DH_ - 1)) >> 1;
    float ang = (float)t * powf(10000.f, -(float)i / 32.f);
    float sn, cs;
    sincosf(ang, &sn, &cs);
    u16* px = qkv + (long)s * QKVW_ + d;
    float x1 = b2f(px[0]), x2 = b2f(px[1]);
    px[0] = f2b(x1 * cs - x2 * sn);
    px[1] = f2b(x1 * sn + x2 * cs);
}

// ---------------------------------------------------------------------------
// MFMA flash attention on fused qkv. grid (T/64, B*H), 4 waves.
// ---------------------------------------------------------------------------
__global__ __launch_bounds__(256, 4) void attn_kernel(const u16* __restrict__ qkv,
                                                      const u16* __restrict__ vtg,
                                                      u16* __restrict__ sab) {
    __shared__ u16 Ks[64 * 64];
    __shared__ u16 Vs[64 * 64];
    __shared__ u16 Ps[4][16 * 64];
    const int tid  = threadIdx.x;
    const int lane = tid & 63;
    const int w    = tid >> 6;
    const int bh = blockIdx.y;
    const int b  = bh >> 4, h = bh & 15;
    const long tok0 = (long)b * T_ + blockIdx.x * 64;
    const int fl = lane & 15;
    const int fq = lane >> 4;

    bf16x8 qf0, qf1;
    {
        const u16* qp = qkv + (tok0 + w * 16 + fl) * QKVW_ + h * 64 + fq * 8;
        qf0 = *(const bf16x8*)qp;
        qf1 = *(const bf16x8*)(qp + 32);
    }

    const int r0 = tid >> 3,  gg0 = tid & 7;
    const int i1 = tid + 256;
    const int r1 = i1 >> 3,   gg1 = i1 & 7;
    const u16* kb0 = qkv + ((long)b * T_) * QKVW_ + 1024 + h * 64;
    const u16* vb0 = vtg + ((long)bh * 64) * T_;

    float m_[4], l_[4];
    f32x4 oacc[4];
#pragma unroll
    for (int i = 0; i < 4; i++) {
        m_[i] = -1e30f; l_[i] = 0.f;
        oacc[i] = (f32x4){0.f, 0.f, 0.f, 0.f};
    }

    for (int kt = 0; kt < T_ / 64; kt++) {
        __syncthreads();
        g2l16(kb0 + (long)(kt * 64 + r0) * QKVW_ + (gg0 ^ (r0 & 7)) * 8, Ks + tid * 8);
        g2l16(kb0 + (long)(kt * 64 + r1) * QKVW_ + (gg1 ^ (r1 & 7)) * 8, Ks + i1 * 8);
        g2l16(vb0 + (long)r0 * T_ + kt * 64 + (gg0 ^ (r0 & 7)) * 8, Vs + tid * 8);
        g2l16(vb0 + (long)r1 * T_ + kt * 64 + (gg1 ^ (r1 & 7)) * 8, Vs + i1 * 8);
        __syncthreads();

        f32x4 sacc[4];
#pragma unroll
        for (int ni = 0; ni < 4; ni++) sacc[ni] = (f32x4){0.f, 0.f, 0.f, 0.f};
#pragma unroll
        for (int ks = 0; ks < 2; ks++) {
            bf16x8 qq = ks ? qf1 : qf0;
#pragma unroll
            for (int ni = 0; ni < 4; ni++) {
                bf16x8 kf = *(const bf16x8*)(Ks + (ni * 16 + fl) * 64 +
                                             (((ks * 4 + fq) ^ (fl & 7)) << 3));
                sacc[ni] = __builtin_amdgcn_mfma_f32_16x16x32_bf16(qq, kf, sacc[ni], 0, 0, 0);
            }
        }

        float rmax[4];
#pragma unroll
        for (int r = 0; r < 4; r++)
            rmax[r] = fmaxf(fmaxf(sacc[0][r], sacc[1][r]),
                            fmaxf(sacc[2][r], sacc[3][r])) * 0.125f;
#pragma unroll
        for (int off = 1; off < 16; off <<= 1)
#pragma unroll
            for (int r = 0; r < 4; r++) rmax[r] = fmaxf(rmax[r], __shfl_xor(rmax[r], off));
        float alpha[4], psum[4];
#pragma unroll
        for (int r = 0; r < 4; r++) {
            float nm = fmaxf(m_[r], rmax[r]);
            alpha[r] = __expf(m_[r] - nm);
            m_[r] = nm;
            psum[r] = 0.f;
        }
        u16* pst = Ps[w];
#pragma unroll
        for (int ni = 0; ni < 4; ni++) {
            int colg = ni * 2 + (fl >> 3);
            int cl   = fl & 7;
#pragma unroll
            for (int r = 0; r < 4; r++) {
                int row = fq * 4 + r;
                float p = __expf(sacc[ni][r] * 0.125f - m_[r]);
                psum[r] += p;
                pst[row * 64 + ((colg ^ (row & 7)) << 3) + cl] = f2b(p);
            }
        }
#pragma unroll
        for (int off = 1; off < 16; off <<= 1)
#pragma unroll
            for (int r = 0; r < 4; r++) psum[r] += __shfl_xor(psum[r], off);
#pragma unroll
        for (int r = 0; r < 4; r++) l_[r] = l_[r] * alpha[r] + psum[r];
#pragma unroll
        for (int ni = 0; ni < 4; ni++)
#pragma unroll
            for (int r = 0; r < 4; r++) oacc[ni][r] *= alpha[r];

#pragma unroll
        for (int ks = 0; ks < 2; ks++) {
            bf16x8 pf = *(const bf16x8*)(pst + fl * 64 +
                                         (((ks * 4 + fq) ^ (fl & 7)) << 3));
#pragma unroll
            for (int ni = 0; ni < 4; ni++) {
                bf16x8 vf = *(const bf16x8*)(Vs + (ni * 16 + fl) * 64 +
                                             (((ks * 4 + fq) ^ (fl & 7)) << 3));
                oacc[ni] = __builtin_amdgcn_mfma_f32_16x16x32_bf16(pf, vf, oacc[ni], 0, 0, 0);
            }
        }
    }

#pragma unroll
    for (int r = 0; r < 4; r++) {
        float inv = 1.f / l_[r];
        u16* op = sab + (tok0 + w * 16 + fq * 4 + r) * D_ + h * 64 + fl;
#pragma unroll
        for (int ni = 0; ni < 4; ni++) op[ni * 16] = f2b(oacc[ni][r] * inv);
    }
}

// ---------------------------------------------------------------------------
// Residual add + RMSNorm. BF=1 additionally writes bf16 copy.
// ---------------------------------------------------------------------------
template<int BF>
__global__ __launch_bounds__(256) void rmsnorm_res(const float* __restrict__ a,
                                                   const float* __restrict__ b,
                                                   const float* __restrict__ w,
                                                   float* __restrict__ outf,
                                                   u16* __restrict__ outb) {
    const int s = blockIdx.x;
    const float* ar = a + (long)s * D_;
    const float* br = b + (long)s * D_;
    float y[4];
    float ss = 0.f;
#pragma unroll
    for (int kx = 0; kx < 4; kx++) {
        int j = threadIdx.x + kx * 256;
        y[kx] = ar[j] + br[j];
        ss += y[kx] * y[kx];
    }
    __shared__ float red[4];
#pragma unroll
    for (int off = 32; off > 0; off >>= 1) ss += __shfl_down(ss, off);
    int lane = threadIdx.x & 63, wv = threadIdx.x >> 6;
    if (lane == 0) red[wv] = ss;
    __syncthreads();
    float tot = red[0] + red[1] + red[2] + red[3];
    float scl = rsqrtf(tot / (float)D_ + EPS_);
    float* orow = outf + (long)s * D_;
#pragma unroll
    for (int kx = 0; kx < 4; kx++) {
        int j = threadIdx.x + kx * 256;
        float v = y[kx] * scl * w[j];
        orow[j] = v;
        if (BF) outb[(long)s * D_ + j] = f2b(v);
    }
}

// ---------------------------------------------------------------------------
// Gating (fp32): one wave per token.
// ---------------------------------------------------------------------------
__global__ __launch_bounds__(256) void gate_kernel(const float* __restrict__ x,
                                                   const float* __restrict__ Wg,
                                                   const float* __restrict__ We,
                                                   const float* __restrict__ gb,
                                                   const float* __restrict__ eb,
                                                   int* __restrict__ tok_e,
                                                   float* __restrict__ tok_w,
                                                   int* __restrict__ counts) {
    const int wave = threadIdx.x >> 6;
    const int lane = threadIdx.x & 63;
    const int s = blockIdx.x * 4 + wave;
    const float* xr = x + (long)s * D_;
    float g0 = 0.f, g1 = 0.f;
    float ee[8];
#pragma unroll
    for (int e = 0; e < 8; e++) ee[e] = 0.f;
    for (int j = lane; j < D_; j += 64) {
        float xv = xr[j];
        g0 += xv * Wg[j * 2 + 0];
        g1 += xv * Wg[j * 2 + 1];
#pragma unroll
        for (int e = 0; e < 8; e++) ee[e] += xv * We[j * 8 + e];
    }
#pragma unroll
    for (int off = 32; off > 0; off >>= 1) {
        g0 += __shfl_down(g0, off);
        g1 += __shfl_down(g1, off);
#pragma unroll
        for (int e = 0; e < 8; e++) ee[e] += __shfl_down(ee[e], off);
    }
    if (lane == 0) {
        g0 += gb[0];
        g1 += gb[1];
        int gidx = (g1 > g0) ? 1 : 0;
        float gm = fmaxf(g0, g1);
        float p0 = expf(g0 - gm), p1 = expf(g1 - gm);
        float gprob = (gidx ? p1 : p0) / (p0 + p1);
        int base = gidx * 4;
        float pe[4];
        float em = -1e30f;
#pragma unroll
        for (int i = 0; i < 4; i++) {
            pe[i] = ee[base + i] + eb[base + i];
            em = fmaxf(em, pe[i]);
        }
        float sum = 0.f;
#pragma unroll
        for (int i = 0; i < 4; i++) { pe[i] = expf(pe[i] - em); sum += pe[i]; }
        float inv = gprob / sum;
#pragma unroll
        for (int i = 0; i < 4; i++) pe[i] *= inv;
        int i1 = 0;
        for (int i = 1; i < 4; i++) if (pe[i] > pe[i1]) i1 = i;
        int i2 = -1;
        for (int i = 0; i < 4; i++) {
            if (i == i1) continue;
            if (i2 < 0 || pe[i] > pe[i2]) i2 = i;
        }
        tok_e[s * 2 + 0] = base + i1;
        tok_e[s * 2 + 1] = base + i2;
        tok_w[s * 2 + 0] = pe[i1];
        tok_w[s * 2 + 1] = pe[i2];
        atomicAdd(&counts[base + i1], 1);
        atomicAdd(&counts[base + i2], 1);
    }
}

__global__ void zero_counts(int* counts) {
    if (threadIdx.x < E_) counts[threadIdx.x] = 0;
}

__global__ void scan_kernel(const int* __restrict__ counts,
                            int* __restrict__ bases,
                            int* __restrict__ cursors) {
    if (threadIdx.x == 0 && blockIdx.x == 0) {
        int acc = 0;
        for (int e = 0; e < E_; e++) {
            bases[e] = acc; cursors[e] = acc; acc += counts[e];
        }
    }
}

__global__ __launch_bounds__(256) void scatter_kernel(const int* __restrict__ tok_e,
                                                      const float* __restrict__ tok_w,
                                                      int* __restrict__ cursors,
                                                      int* __restrict__ list,
                                                      float* __restrict__ wlist) {
    int s = blockIdx.x * 256 + threadIdx.x;
    if (s >= S_) return;
#pragma unroll
    for (int t = 0; t < 2; t++) {
        int e = tok_e[s * 2 + t];
        int pos = atomicAdd(&cursors[e], 1);
        list[pos] = s;
        wlist[pos] = tok_w[s * 2 + t];
    }
}

// ---------------------------------------------------------------------------
extern "C" void kernel_launch(void* const* d_in, const int* in_sizes, int n_in,
                              void* d_out, int out_size, void* d_ws, size_t ws_size,
                              hipStream_t stream) {
    const float* src  = (const float*)d_in[0];
    const float* Wq   = (const float*)d_in[1];
    const float* Wk_c = (const float*)d_in[2];
    const float* Wv_c = (const float*)d_in[3];
    const float* Wk   = (const float*)d_in[4];
    const float* Wv   = (const float*)d_in[5];
    const float* Wo   = (const float*)d_in[6];
    const float* Wsin = (const float*)d_in[7];
    const float* Wsout= (const float*)d_in[8];
    const float* W1   = (const float*)d_in[9];
    const float* W2   = (const float*)d_in[10];
    const float* Wg   = (const float*)d_in[11];
    const float* We   = (const float*)d_in[12];
    const float* gb   = (const float*)d_in[13];
    const float* eb   = (const float*)d_in[14];
    const float* n1w  = (const float*)d_in[15];
    const float* n2w  = (const float*)d_in[16];
    float* out = (float*)d_out;

    const size_t MB = 1u << 20;
    char* w8 = (char*)d_ws;
    // Layout (MB offsets), overlays noted. Lifetimes verified:
    u16*  qkv   = (u16*)(w8);              // 0..24  (S x 3072 bf16); dead after attn
    u16*  vtg   = (u16*)(w8 + 24 * MB);    // 24..32; dead after attn
    u16*  w2t   = (u16*)(w8);              // 0..32  (overlays qkv+vtg, late; ends at exactly 32 MB)
    u16*  WkcB  = (u16*)(w8 + 24 * MB);    // temps (overlay vtg, early, dead before vt_conv)
    u16*  WvcB  = (u16*)(w8 + 24 * MB + 512 * 1024);
    u16*  WkTs  = (u16*)(w8 + 25 * MB);
    u16*  WvTs  = (u16*)(w8 + 25 * MB + 512 * 1024);
    u16*  sab   = (u16*)(w8 + 32 * MB);    // 32..40; dead after Wo gemm
    // small gating arrays overlay sab's first ~130 KB, used only after sab dead
    float* tokw = (float*)(w8 + 32 * MB);
    float* wlist = tokw + 2 * S_;
    int* toke   = (int*)(wlist + 2 * S_);
    int* list   = toke + 2 * S_;
    int* counts = list + 2 * S_;
    int* bases  = counts + E_;
    int* cursors= bases + E_;
    float* x1   = (float*)(w8 + 40 * MB);  // 40..56
    float* ffn  = (float*)(w8 + 56 * MB);  // 56..72
    u16*  x1b   = (u16*)(w8 + 72 * MB);    // 72..80
    u16*  hbuf  = (u16*)(w8 + 80 * MB);    // 80..96
    u16*  srcb  = (u16*)(w8 + 96 * MB);    // 96..104 (early)
    float* oproj= (float*)(w8 + 96 * MB);  // 96..112 (after srcb dead)
    u16*  WqkvT = (u16*)(w8 + 112 * MB);   // 112..118 (early)
    u16*  WsoutT= (u16*)(w8 + 112 * MB);   // 112..116 (after WqkvT dead)
    u16*  WoT   = (u16*)(w8 + 118 * MB);   // 118..120
    u16*  WsinT = (u16*)(w8 + 120 * MB);   // 120..128
    u16*  W1T   = (u16*)(w8 + 128 * MB);   // 128..136

    dim3 blk(256);

    // --- build fused QKV weight (3072 x 1024 bf16, Bt layout) ---
    conv_t<<<dim3(32, 32), blk, 0, stream>>>(Wq, WqkvT, 1024, 1024, 0, 0, 0);
    convert_bf16<<<dim3(D_ * DC_ / 4 / 256), blk, 0, stream>>>(Wk_c, WkcB, D_ * DC_ / 4);
    convert_bf16<<<dim3(D_ * DC_ / 4 / 256), blk, 0, stream>>>(Wv_c, WvcB, D_ * DC_ / 4);
    conv_t<<<dim3(32, 8), blk, 0, stream>>>(Wk, WkTs, 256, 1024, 0, 0, 0);
    conv_t<<<dim3(32, 8), blk, 0, stream>>>(Wv, WvTs, 256, 1024, 0, 0, 0);
    // (Wk_c@Wk)^T, (Wv_c@Wv)^T  (OUTMODE=2 transposed store, ldo=M=1024)
    gemm_bf16<2><<<dim3(8, 8), blk, 0, stream>>>(WkcB, WkTs, WqkvT + 1024 * 1024, 1024, 256, 1024);
    gemm_bf16<2><<<dim3(8, 8), blk, 0, stream>>>(WvcB, WvTs, WqkvT + 2048 * 1024, 1024, 256, 1024);

    convert_bf16<<<dim3(S_ * D_ / 4 / 256), blk, 0, stream>>>(src, srcb, S_ * D_ / 4);

    // Fused QKV projection: (S,1024) @ (1024,3072) -> qkv (S,3072)
    gemm_bf16<1><<<dim3(24, 32), blk, 0, stream>>>(srcb, WqkvT, qkv, QKVW_, 1024, QKVW_);

    // other weight conversions (WqkvT dead after the QKV gemm; WsoutT overlays it)
    conv_t<<<dim3(32, 32), blk, 0, stream>>>(Wo, WoT, 1024, 1024, 0, 0, 0);
    conv_t<<<dim3(128, 32), blk, 0, stream>>>(Wsin, WsinT, 1024, 4096, 0, 0, 1);
    conv_t<<<dim3(32, 64), blk, 0, stream>>>(Wsout, WsoutT, 2048, 1024, 0, 0, 0);
    conv_t<<<dim3(128, 32), blk, 0, stream>>>(W1, W1T, 1024, 4096, 0, 0, 1);

    // RoPE on q,k halves (one launch)
    rope_kernel<<<dim3(S_ * 2048 / 2 / 256), blk, 0, stream>>>(qkv);

    vt_conv<<<dim3(T_ / 32, 2, B_ * H_), blk, 0, stream>>>(qkv, vtg);
    attn_kernel<<<dim3(T_ / 64, B_ * H_), blk, 0, stream>>>(qkv, vtg, sab);

    gemm_bf16<0><<<dim3(8, 32), blk, 0, stream>>>(sab, WoT, oproj, 1024, 1024, 1024);
    rmsnorm_res<1><<<dim3(S_), blk, 0, stream>>>(src, oproj, n1w, x1, x1b);

    // Shared FFN with fused swiglu epilogue -> hbuf (S,2048)
    gemm_bf16<3><<<dim3(32, 32), blk, 0, stream>>>(x1b, WsinT, hbuf, 4096, 1024, 2048);
    gemm_bf16<0><<<dim3(8, 32), blk, 0, stream>>>(hbuf, WsoutT, ffn, 1024, 2048, 1024);

    // Gating (small arrays live in dead sab region; zero AFTER sab last use)
    zero_counts<<<dim3(1), dim3(64), 0, stream>>>(counts);
    gate_kernel<<<dim3(S_ / 4), blk, 0, stream>>>(x1, Wg, We, gb, eb, toke, tokw, counts);
    scan_kernel<<<dim3(1), dim3(1), 0, stream>>>(counts, bases, cursors);
    scatter_kernel<<<dim3(S_ / 256), blk, 0, stream>>>(toke, tokw, cursors, list, wlist);

    // Routed experts (W1 with fused swiglu, then gathered W2 GEMM)
    gemm_bf16<3><<<dim3(32, 32), blk, 0, stream>>>(x1b, W1T, hbuf, 4096, 1024, 2048);
    conv_t<<<dim3(32, 64, 8), blk, 0, stream>>>(W2, w2t, 2048, 1024,
                                                (long)HID_ * D_, (long)D_ * HID_, 0);
    routed_gemm<<<dim3(8, E_ * 32), blk, 0, stream>>>(hbuf, w2t, list, wlist,
                                                      bases, counts, ffn);

    rmsnorm_res<0><<<dim3(S_), blk, 0, stream>>>(x1, ffn, n2w, out, (u16*)nullptr);
}

// Round 6
// 809.728 us; speedup vs baseline: 5.3959x; 1.0047x over previous
//
#include <hip/hip_runtime.h>
#include <math.h>

#define D_    1024
#define H_    16
#define DH_   64
#define DC_   256
#define HID_  2048
#define E_    8
#define B_    2
#define T_    2048
#define S_    4096
#define EPS_  1e-6f
#define QKVW_ 3072   // fused qkv row width

typedef unsigned short u16;
typedef short bf16x8 __attribute__((ext_vector_type(8)));
typedef float f32x4 __attribute__((ext_vector_type(4)));

__device__ __forceinline__ float b2f(u16 u) {
    return __uint_as_float(((unsigned int)u) << 16);
}
__device__ __forceinline__ u16 f2b(float f) {
    unsigned int u = __float_as_uint(f);
    u += 0x7FFF + ((u >> 16) & 1);
    return (u16)(u >> 16);
}
__device__ __forceinline__ void g2l16(const u16* g, u16* l) {
    __builtin_amdgcn_global_load_lds(
        (const __attribute__((address_space(1))) void*)g,
        (__attribute__((address_space(3))) void*)l, 16, 0, 0);
}

// ---------------------------------------------------------------------------
// Transpose + fp32->bf16: in (K,N) fp32 -> out (N,K) bf16.
// perm=1: swiglu column interleave for fused epilogue.
// ---------------------------------------------------------------------------
__global__ __launch_bounds__(256) void conv_t(const float* __restrict__ in,
                                              u16* __restrict__ out,
                                              int K, int N,
                                              long inZ, long outZ, int perm) {
    in  += (long)blockIdx.z * inZ;
    out += (long)blockIdx.z * outZ;
    __shared__ float t[32][33];
    const int n0 = blockIdx.x * 32, k0 = blockIdx.y * 32;
    int src_n0 = n0;
    if (perm) {
        int t64 = n0 >> 6;
        src_n0 = ((n0 & 63) == 0) ? t64 * 32 : (N / 2 + t64 * 32);
    }
    const int tx = threadIdx.x & 31, ty = threadIdx.x >> 5;
#pragma unroll
    for (int i = 0; i < 4; i++)
        t[ty + 8 * i][tx] = in[(long)(k0 + ty + 8 * i) * N + src_n0 + tx];
    __syncthreads();
#pragma unroll
    for (int i = 0; i < 4; i++)
        out[(long)(n0 + ty + 8 * i) * K + k0 + tx] = f2b(t[tx][ty + 8 * i]);
}

// bf16 transpose V rows of fused qkv (stride QKVW_) per-head -> Vt [bh][64][T]
__global__ __launch_bounds__(256) void vt_conv(const u16* __restrict__ qkv,
                                               u16* __restrict__ vt) {
    __shared__ u16 t[32][34];
    const int bh = blockIdx.z;
    const int b = bh >> 4, h = bh & 15;
    const int t0 = blockIdx.x * 32, d0 = blockIdx.y * 32;
    const int tx = threadIdx.x & 31, ty = threadIdx.x >> 5;
#pragma unroll
    for (int i = 0; i < 4; i++)
        t[ty + 8 * i][tx] =
            qkv[((long)b * T_ + t0 + ty + 8 * i) * QKVW_ + 2048 + h * 64 + d0 + tx];
    __syncthreads();
#pragma unroll
    for (int i = 0; i < 4; i++)
        vt[((long)bh * 64 + d0 + ty + 8 * i) * T_ + t0 + tx] = t[tx][ty + 8 * i];
}

// Elementwise fp32 -> bf16
__global__ __launch_bounds__(256) void convert_bf16(const float* __restrict__ in,
                                                    u16* __restrict__ out, int n4) {
    int i = blockIdx.x * 256 + threadIdx.x;
    if (i >= n4) return;
    float4 f = ((const float4*)in)[i];
    ushort4 o;
    o.x = f2b(f.x); o.y = f2b(f.y); o.z = f2b(f.z); o.w = f2b(f.w);
    ((ushort4*)out)[i] = o;
}

// ---------------------------------------------------------------------------
// bf16 MFMA GEMM: C(M,N) = A(M,K) @ Bt(N,K)^T. 128x128, BK=32, 4 waves.
// Split-K via blockIdx.z (use OUTMODE 4 when gridDim.z > 1).
// OUTMODE 0: fp32 store | 1: bf16 store | 2: bf16 transposed store (ldo=M)
// OUTMODE 3: swiglu epilogue, dual output: rows of Bt >= 4096 (blockIdx.x>=32)
//            write to Cp + S_*HID_ (hbuf2). ldo = HID_.
// OUTMODE 4: fp32 atomicAdd (split-K accumulate)
// ---------------------------------------------------------------------------
template<int OUTMODE>
__global__ __launch_bounds__(256) void gemm_bf16(const u16* __restrict__ A,
                                                 const u16* __restrict__ Bt,
                                                 void* __restrict__ Cp,
                                                 int N, int K, int ldo) {
    __shared__ u16 As[128 * 32];
    __shared__ u16 Bs[128 * 32];
    const int tid  = threadIdx.x;
    const int lane = tid & 63;
    const int wv   = tid >> 6;
    const int wm   = wv >> 1, wn = wv & 1;
    const long row0 = (long)blockIdx.y * 128;
    const long col0 = (long)blockIdx.x * 128;
    const int Klocal = K / gridDim.z;
    const long koff  = (long)blockIdx.z * Klocal;

    f32x4 acc[4][4];
#pragma unroll
    for (int i = 0; i < 4; i++)
#pragma unroll
        for (int j = 0; j < 4; j++) acc[i][j] = (f32x4){0.f, 0.f, 0.f, 0.f};

    const int sr = tid >> 2;
    const int sc = (tid & 3) << 3;
    const u16* Ag  = A  + (row0 + sr) * (long)K + koff + sc;
    const u16* Ag2 = Ag + 64 * (long)K;
    const u16* Bg  = Bt + (col0 + sr) * (long)K + koff + sc;
    const u16* Bg2 = Bg + 64 * (long)K;
    u16* lA  = As + tid * 8;
    u16* lA2 = As + 2048 + tid * 8;
    u16* lB  = Bs + tid * 8;
    u16* lB2 = Bs + 2048 + tid * 8;

    const int fl = lane & 15;
    const int fk = (lane >> 4) << 3;
    const u16* ArA = As + (wm * 64 + fl) * 32 + fk;
    const u16* BrB = Bs + (wn * 64 + fl) * 32 + fk;

    for (int k0 = 0; k0 < Klocal; k0 += 32) {
        __syncthreads();
        g2l16(Ag + k0, lA);
        g2l16(Ag2 + k0, lA2);
        g2l16(Bg + k0, lB);
        g2l16(Bg2 + k0, lB2);
        __syncthreads();
        bf16x8 af[4], bfr[4];
#pragma unroll
        for (int mi = 0; mi < 4; mi++) af[mi]  = *(const bf16x8*)(ArA + mi * 512);
#pragma unroll
        for (int ni = 0; ni < 4; ni++) bfr[ni] = *(const bf16x8*)(BrB + ni * 512);
#pragma unroll
        for (int mi = 0; mi < 4; mi++)
#pragma unroll
            for (int ni = 0; ni < 4; ni++)
                acc[mi][ni] = __builtin_amdgcn_mfma_f32_16x16x32_bf16(
                    af[mi], bfr[ni], acc[mi][ni], 0, 0, 0);
    }

    const int cr = (lane >> 4) << 2;
    const int cc = lane & 15;
#pragma unroll
    for (int mi = 0; mi < 4; mi++) {
#pragma unroll
        for (int r = 0; r < 4; r++) {
            long grow = row0 + wm * 64 + mi * 16 + cr + r;
            if (OUTMODE == 3) {
                u16* outb = (u16*)Cp + (long)(blockIdx.x >> 5) * S_ * HID_;
                u16* hrow = outb + grow * ldo + (blockIdx.x & 31) * 64 + wn * 32;
#pragma unroll
                for (int ni = 0; ni < 2; ni++) {
                    float a = acc[mi][ni][r], b = acc[mi][ni + 2][r];
                    float sig = 1.f / (1.f + __expf(-a));
                    hrow[ni * 16 + cc] = f2b(a * sig * b);
                }
            } else {
#pragma unroll
                for (int ni = 0; ni < 4; ni++) {
                    long gcol = col0 + wn * 64 + ni * 16 + cc;
                    float v = acc[mi][ni][r];
                    if (OUTMODE == 0)      ((float*)Cp)[grow * ldo + gcol] = v;
                    else if (OUTMODE == 1) ((u16*)Cp)[grow * ldo + gcol] = f2b(v);
                    else if (OUTMODE == 2) ((u16*)Cp)[gcol * ldo + grow] = f2b(v);
                    else atomicAdd((float*)Cp + grow * ldo + gcol, v);
                }
            }
        }
    }
}

// ---------------------------------------------------------------------------
// Routed-expert bf16 MFMA GEMM (gathered rows, scaled atomicAdd epilogue)
// ---------------------------------------------------------------------------
__global__ __launch_bounds__(256) void routed_gemm(const u16* __restrict__ Hh,
                                                   const u16* __restrict__ W2T,
                                                   const int* __restrict__ list,
                                                   const float* __restrict__ wlist,
                                                   const int* __restrict__ bases,
                                                   const int* __restrict__ counts,
                                                   float* __restrict__ Cout) {
    const int e    = blockIdx.y >> 5;
    const int tile = blockIdx.y & 31;
    const int cnt  = counts[e];
    if (tile * 128 >= cnt) return;
    const int base = bases[e];

    __shared__ u16 As[128 * 32];
    __shared__ u16 Bs[128 * 32];
    __shared__ int   toks[128];
    __shared__ float wrow[128];

    const int tid = threadIdx.x;
    if (tid < 128) {
        int ridx = tile * 128 + tid;
        if (ridx < cnt) { toks[tid] = list[base + ridx]; wrow[tid] = wlist[base + ridx]; }
        else            { toks[tid] = -1;                wrow[tid] = 0.f; }
    }
    __syncthreads();

    const int lane = tid & 63;
    const int wv   = tid >> 6;
    const int wm   = wv >> 1, wn = wv & 1;
    const long col0 = (long)blockIdx.x * 128;

    f32x4 acc[4][4];
#pragma unroll
    for (int i = 0; i < 4; i++)
#pragma unroll
        for (int j = 0; j < 4; j++) acc[i][j] = (f32x4){0.f, 0.f, 0.f, 0.f};

    const int sr = tid >> 2;
    const int sc = (tid & 3) << 3;
    const int t1 = toks[sr], t2 = toks[sr + 64];
    const u16* Ag  = Hh + (long)(t1 < 0 ? 0 : t1) * HID_ + sc;
    const u16* Ag2 = Hh + (long)(t2 < 0 ? 0 : t2) * HID_ + sc;
    const u16* Bg  = W2T + (long)e * D_ * HID_ + (col0 + sr) * (long)HID_ + sc;
    const u16* Bg2 = Bg + 64 * (long)HID_;
    u16* lA  = As + tid * 8;
    u16* lA2 = As + 2048 + tid * 8;
    u16* lB  = Bs + tid * 8;
    u16* lB2 = Bs + 2048 + tid * 8;

    const int fl = lane & 15;
    const int fk = (lane >> 4) << 3;
    const u16* ArA = As + (wm * 64 + fl) * 32 + fk;
    const u16* BrB = Bs + (wn * 64 + fl) * 32 + fk;

    for (int k0 = 0; k0 < HID_; k0 += 32) {
        __syncthreads();
        g2l16(Ag + k0, lA);
        g2l16(Ag2 + k0, lA2);
        g2l16(Bg + k0, lB);
        g2l16(Bg2 + k0, lB2);
        __syncthreads();
        bf16x8 af[4], bfr[4];
#pragma unroll
        for (int mi = 0; mi < 4; mi++) af[mi]  = *(const bf16x8*)(ArA + mi * 512);
#pragma unroll
        for (int ni = 0; ni < 4; ni++) bfr[ni] = *(const bf16x8*)(BrB + ni * 512);
#pragma unroll
        for (int mi = 0; mi < 4; mi++)
#pragma unroll
            for (int ni = 0; ni < 4; ni++)
                acc[mi][ni] = __builtin_amdgcn_mfma_f32_16x16x32_bf16(
                    af[mi], bfr[ni], acc[mi][ni], 0, 0, 0);
    }

    const int cr = (lane >> 4) << 2;
    const int cc = lane & 15;
#pragma unroll
    for (int mi = 0; mi < 4; mi++) {
#pragma unroll
        for (int r = 0; r < 4; r++) {
            int rr = wm * 64 + mi * 16 + cr + r;
            int tk = toks[rr];
            if (tk < 0) continue;
            float wvw = wrow[rr];
            float* crow = Cout + (long)tk * D_ + col0 + wn * 64;
#pragma unroll
            for (int ni = 0; ni < 4; ni++)
                atomicAdd(crow + ni * 16 + cc, acc[mi][ni][r] * wvw);
        }
    }
}

// ---------------------------------------------------------------------------
// RoPE: sincos table (T_ x 32) then vectorized apply on q,k cols of qkv.
// ---------------------------------------------------------------------------
__global__ __launch_bounds__(256) void rope_table(float2* __restrict__ tab) {
    int idx = blockIdx.x * 256 + threadIdx.x;     // 65536
    int t = idx >> 5, i = idx & 31;
    float ang = (float)t * powf(10000.f, -(float)i / 32.f);
    float sn, cs;
    sincosf(ang, &sn, &cs);
    tab[idx] = make_float2(sn, cs);
}

__global__ __launch_bounds__(256) void rope_apply(u16* __restrict__ qkv,
                                                  const float2* __restrict__ tab) {
    long p = (long)blockIdx.x * 256 + threadIdx.x;   // S_*2048/8 groups
    int s  = (int)(p >> 8);
    int c8 = (int)(p & 255) << 3;
    int t  = s & (T_ - 1);
    const float2* tp = tab + t * 32 + ((c8 & 63) >> 1);
    u16* px = qkv + (long)s * QKVW_ + c8;
    bf16x8 v = *(const bf16x8*)px;
    bf16x8 o;
#pragma unroll
    for (int j = 0; j < 4; j++) {
        float x1 = b2f((u16)v[2 * j]), x2 = b2f((u16)v[2 * j + 1]);
        float2 sc = tp[j];
        o[2 * j]     = (short)f2b(x1 * sc.y - x2 * sc.x);
        o[2 * j + 1] = (short)f2b(x1 * sc.x + x2 * sc.y);
    }
    *(bf16x8*)px = o;
}

// ---------------------------------------------------------------------------
// MFMA flash attention, 128-key tiles. grid (T/64, B*H), 4 waves x 16 q-rows.
// LDS: Ks 128x64, Vs 64x128, Ps 4 x 16x128 (XOR-swizzled 16B groups). 48 KB.
// ---------------------------------------------------------------------------
__global__ __launch_bounds__(256) void attn_kernel(const u16* __restrict__ qkv,
                                                   const u16* __restrict__ vtg,
                                                   u16* __restrict__ sab) {
    __shared__ u16 Ks[128 * 64];
    __shared__ u16 Vs[64 * 128];
    __shared__ u16 Ps[4][16 * 128];
    const int tid  = threadIdx.x;
    const int lane = tid & 63;
    const int w    = tid >> 6;
    const int bh = blockIdx.y;
    const int b  = bh >> 4, h = bh & 15;
    const long tok0 = (long)b * T_ + blockIdx.x * 64;
    const int fl = lane & 15;
    const int fq = lane >> 4;

    bf16x8 qf0, qf1;
    {
        const u16* qp = qkv + (tok0 + w * 16 + fl) * QKVW_ + h * 64 + fq * 8;
        qf0 = *(const bf16x8*)qp;
        qf1 = *(const bf16x8*)(qp + 32);
    }

    const u16* kb0 = qkv + ((long)b * T_) * QKVW_ + 1024 + h * 64;
    const u16* vb0 = vtg + ((long)bh * 64) * T_;

    float m_[4], l_[4];
    f32x4 oacc[4];
#pragma unroll
    for (int i = 0; i < 4; i++) {
        m_[i] = -1e30f; l_[i] = 0.f;
        oacc[i] = (f32x4){0.f, 0.f, 0.f, 0.f};
    }

    for (int kt = 0; kt < T_ / 128; kt++) {
        __syncthreads();
        // K: 1024 slots (row=i>>3 of 128 keys, grp=i&7 of 8), 4 passes
#pragma unroll
        for (int ps = 0; ps < 4; ps++) {
            int i = tid + ps * 256;
            int row = i >> 3, gg = i & 7;
            g2l16(kb0 + (long)(kt * 128 + row) * QKVW_ + ((gg ^ (row & 7)) << 3),
                  Ks + i * 8);
        }
        // V: 1024 slots (row=i>>4 of 64 d, grp=i&15 of 16), 4 passes
#pragma unroll
        for (int ps = 0; ps < 4; ps++) {
            int i = tid + ps * 256;
            int row = i >> 4, gg = i & 15;
            g2l16(vb0 + (long)row * T_ + kt * 128 + ((gg ^ (row & 15)) << 3),
                  Vs + i * 8);
        }
        __syncthreads();

        // S = Q K^T  (16 q-rows x 128 k-cols per wave)
        f32x4 sacc[8];
#pragma unroll
        for (int ni = 0; ni < 8; ni++) sacc[ni] = (f32x4){0.f, 0.f, 0.f, 0.f};
#pragma unroll
        for (int ks = 0; ks < 2; ks++) {
            bf16x8 qq = ks ? qf1 : qf0;
#pragma unroll
            for (int ni = 0; ni < 8; ni++) {
                bf16x8 kf = *(const bf16x8*)(Ks + (ni * 16 + fl) * 64 +
                                             (((ks * 4 + fq) ^ (fl & 7)) << 3));
                sacc[ni] = __builtin_amdgcn_mfma_f32_16x16x32_bf16(qq, kf, sacc[ni], 0, 0, 0);
            }
        }

        float rmax[4];
#pragma unroll
        for (int r = 0; r < 4; r++) {
            float mm = sacc[0][r];
#pragma unroll
            for (int ni = 1; ni < 8; ni++) mm = fmaxf(mm, sacc[ni][r]);
            rmax[r] = mm * 0.125f;
        }
#pragma unroll
        for (int off = 1; off < 16; off <<= 1)
#pragma unroll
            for (int r = 0; r < 4; r++) rmax[r] = fmaxf(rmax[r], __shfl_xor(rmax[r], off));
        float alpha[4], psum[4];
#pragma unroll
        for (int r = 0; r < 4; r++) {
            float nm = fmaxf(m_[r], rmax[r]);
            alpha[r] = __expf(m_[r] - nm);
            m_[r] = nm;
            psum[r] = 0.f;
        }
        u16* pst = Ps[w];
#pragma unroll
        for (int ni = 0; ni < 8; ni++) {
            int colg = ni * 2 + (fl >> 3);
            int cl   = fl & 7;
#pragma unroll
            for (int r = 0; r < 4; r++) {
                int row = fq * 4 + r;
                float p = __expf(sacc[ni][r] * 0.125f - m_[r]);
                psum[r] += p;
                pst[row * 128 + ((colg ^ (row & 15)) << 3) + cl] = f2b(p);
            }
        }
#pragma unroll
        for (int off = 1; off < 16; off <<= 1)
#pragma unroll
            for (int r = 0; r < 4; r++) psum[r] += __shfl_xor(psum[r], off);
#pragma unroll
        for (int r = 0; r < 4; r++) l_[r] = l_[r] * alpha[r] + psum[r];
#pragma unroll
        for (int ni = 0; ni < 4; ni++)
#pragma unroll
            for (int r = 0; r < 4; r++) oacc[ni][r] *= alpha[r];

        // O += P V   (K=128 over 4 ks steps)
#pragma unroll
        for (int ks = 0; ks < 4; ks++) {
            bf16x8 pf = *(const bf16x8*)(pst + fl * 128 +
                                         (((ks * 4 + fq) ^ fl) << 3));
#pragma unroll
            for (int ni = 0; ni < 4; ni++) {
                bf16x8 vf = *(const bf16x8*)(Vs + (ni * 16 + fl) * 128 +
                                             (((ks * 4 + fq) ^ fl) << 3));
                oacc[ni] = __builtin_amdgcn_mfma_f32_16x16x32_bf16(pf, vf, oacc[ni], 0, 0, 0);
            }
        }
    }

#pragma unroll
    for (int r = 0; r < 4; r++) {
        float inv = 1.f / l_[r];
        u16* op = sab + (tok0 + w * 16 + fq * 4 + r) * D_ + h * 64 + fl;
#pragma unroll
        for (int ni = 0; ni < 4; ni++) op[ni * 16] = f2b(oacc[ni][r] * inv);
    }
}

// ---------------------------------------------------------------------------
// Residual add + RMSNorm. BF=1 additionally writes bf16 copy.
// ---------------------------------------------------------------------------
template<int BF>
__global__ __launch_bounds__(256) void rmsnorm_res(const float* __restrict__ a,
                                                   const float* __restrict__ b,
                                                   const float* __restrict__ w,
                                                   float* __restrict__ outf,
                                                   u16* __restrict__ outb) {
    const int s = blockIdx.x;
    const float* ar = a + (long)s * D_;
    const float* br = b + (long)s * D_;
    float y[4];
    float ss = 0.f;
#pragma unroll
    for (int kx = 0; kx < 4; kx++) {
        int j = threadIdx.x + kx * 256;
        y[kx] = ar[j] + br[j];
        ss += y[kx] * y[kx];
    }
    __shared__ float red[4];
#pragma unroll
    for (int off = 32; off > 0; off >>= 1) ss += __shfl_down(ss, off);
    int lane = threadIdx.x & 63, wv = threadIdx.x >> 6;
    if (lane == 0) red[wv] = ss;
    __syncthreads();
    float tot = red[0] + red[1] + red[2] + red[3];
    float scl = rsqrtf(tot / (float)D_ + EPS_);
    float* orow = outf + (long)s * D_;
#pragma unroll
    for (int kx = 0; kx < 4; kx++) {
        int j = threadIdx.x + kx * 256;
        float v = y[kx] * scl * w[j];
        orow[j] = v;
        if (BF) outb[(long)s * D_ + j] = f2b(v);
    }
}

// ---------------------------------------------------------------------------
// Gating (fp32): one wave per token.
// ---------------------------------------------------------------------------
__global__ __launch_bounds__(256) void gate_kernel(const float* __restrict__ x,
                                                   const float* __restrict__ Wg,
                                                   const float* __restrict__ We,
                                                   const float* __restrict__ gb,
                                                   const float* __restrict__ eb,
                                                   int* __restrict__ tok_e,
                                                   float* __restrict__ tok_w,
                                                   int* __restrict__ counts) {
    const int wave = threadIdx.x >> 6;
    const int lane = threadIdx.x & 63;
    const int s = blockIdx.x * 4 + wave;
    const float* xr = x + (long)s * D_;
    float g0 = 0.f, g1 = 0.f;
    float ee[8];
#pragma unroll
    for (int e = 0; e < 8; e++) ee[e] = 0.f;
    for (int j = lane; j < D_; j += 64) {
        float xv = xr[j];
        g0 += xv * Wg[j * 2 + 0];
        g1 += xv * Wg[j * 2 + 1];
#pragma unroll
        for (int e = 0; e < 8; e++) ee[e] += xv * We[j * 8 + e];
    }
#pragma unroll
    for (int off = 32; off > 0; off >>= 1) {
        g0 += __shfl_down(g0, off);
        g1 += __shfl_down(g1, off);
#pragma unroll
        for (int e = 0; e < 8; e++) ee[e] += __shfl_down(ee[e], off);
    }
    if (lane == 0) {
        g0 += gb[0];
        g1 += gb[1];
        int gidx = (g1 > g0) ? 1 : 0;
        float gm = fmaxf(g0, g1);
        float p0 = expf(g0 - gm), p1 = expf(g1 - gm);
        float gprob = (gidx ? p1 : p0) / (p0 + p1);
        int base = gidx * 4;
        float pe[4];
        float em = -1e30f;
#pragma unroll
        for (int i = 0; i < 4; i++) {
            pe[i] = ee[base + i] + eb[base + i];
            em = fmaxf(em, pe[i]);
        }
        float sum = 0.f;
#pragma unroll
        for (int i = 0; i < 4; i++) { pe[i] = expf(pe[i] - em); sum += pe[i]; }
        float inv = gprob / sum;
#pragma unroll
        for (int i = 0; i < 4; i++) pe[i] *= inv;
        int i1 = 0;
        for (int i = 1; i < 4; i++) if (pe[i] > pe[i1]) i1 = i;
        int i2 = -1;
        for (int i = 0; i < 4; i++) {
            if (i == i1) continue;
            if (i2 < 0 || pe[i] > pe[i2]) i2 = i;
        }
        tok_e[s * 2 + 0] = base + i1;
        tok_e[s * 2 + 1] = base + i2;
        tok_w[s * 2 + 0] = pe[i1];
        tok_w[s * 2 + 1] = pe[i2];
        atomicAdd(&counts[base + i1], 1);
        atomicAdd(&counts[base + i2], 1);
    }
}

__global__ void zero_counts(int* counts) {
    if (threadIdx.x < E_) counts[threadIdx.x] = 0;
}

__global__ void scan_kernel(const int* __restrict__ counts,
                            int* __restrict__ bases,
                            int* __restrict__ cursors) {
    if (threadIdx.x == 0 && blockIdx.x == 0) {
        int acc = 0;
        for (int e = 0; e < E_; e++) {
            bases[e] = acc; cursors[e] = acc; acc += counts[e];
        }
    }
}

__global__ __launch_bounds__(256) void scatter_kernel(const int* __restrict__ tok_e,
                                                      const float* __restrict__ tok_w,
                                                      int* __restrict__ cursors,
                                                      int* __restrict__ list,
                                                      float* __restrict__ wlist) {
    int s = blockIdx.x * 256 + threadIdx.x;
    if (s >= S_) return;
#pragma unroll
    for (int t = 0; t < 2; t++) {
        int e = tok_e[s * 2 + t];
        int pos = atomicAdd(&cursors[e], 1);
        list[pos] = s;
        wlist[pos] = tok_w[s * 2 + t];
    }
}

// ---------------------------------------------------------------------------
extern "C" void kernel_launch(void* const* d_in, const int* in_sizes, int n_in,
                              void* d_out, int out_size, void* d_ws, size_t ws_size,
                              hipStream_t stream) {
    const float* src  = (const float*)d_in[0];
    const float* Wq   = (const float*)d_in[1];
    const float* Wk_c = (const float*)d_in[2];
    const float* Wv_c = (const float*)d_in[3];
    const float* Wk   = (const float*)d_in[4];
    const float* Wv   = (const float*)d_in[5];
    const float* Wo   = (const float*)d_in[6];
    const float* Wsin = (const float*)d_in[7];
    const float* Wsout= (const float*)d_in[8];
    const float* W1   = (const float*)d_in[9];
    const float* W2   = (const float*)d_in[10];
    const float* Wg   = (const float*)d_in[11];
    const float* We   = (const float*)d_in[12];
    const float* gb   = (const float*)d_in[13];
    const float* eb   = (const float*)d_in[14];
    const float* n1w  = (const float*)d_in[15];
    const float* n2w  = (const float*)d_in[16];
    float* out = (float*)d_out;

    const size_t MB = 1u << 20;
    char* w8 = (char*)d_ws;
    // Layout (MiB offsets). Lifetimes:
    u16*  qkv   = (u16*)(w8);              // 0..24; dead after attn
    u16*  vtg   = (u16*)(w8 + 24 * MB);    // 24..32; dead after attn
    u16*  w2t   = (u16*)(w8);              // 0..32 (late, after qkv/vtg dead)
    u16*  WkcB  = (u16*)(w8 + 24 * MB);    // early temps (dead before vt_conv)
    u16*  WvcB  = (u16*)(w8 + 24 * MB + 512 * 1024);
    u16*  WkTs  = (u16*)(w8 + 25 * MB);
    u16*  WvTs  = (u16*)(w8 + 25 * MB + 512 * 1024);
    u16*  sab   = (u16*)(w8 + 32 * MB);    // 32..40; dead after Wo gemm
    float* tokw = (float*)(w8 + 32 * MB);  // gating arrays overlay dead sab
    float* wlist = tokw + 2 * S_;
    int* toke   = (int*)(wlist + 2 * S_);
    int* list   = toke + 2 * S_;
    int* counts = list + 2 * S_;
    int* bases  = counts + E_;
    int* cursors= bases + E_;
    float* x1   = (float*)(w8 + 40 * MB);  // 40..56
    float* ffn  = (float*)(w8 + 56 * MB);  // 56..72
    u16*  x1b   = (u16*)(w8 + 72 * MB);    // 72..80
    u16*  hbuf  = (u16*)(w8 + 80 * MB);    // 80..96 (shared-FFN h)
    u16*  srcb  = (u16*)(w8 + 96 * MB);    // 96..104 (early; dead after QKV gemm)
    float2* rtab= (float2*)(w8 + 104 * MB);// 104..104.5 (dead before Wo gemm)
    float* oproj= (float*)(w8 + 96 * MB);  // 96..112 (Wo out; dead after rmsnorm1)
    u16*  hbuf2 = (u16*)(w8 + 96 * MB);    // 96..112 (routed h; after oproj dead)
    u16*  WqkvT = (u16*)(w8 + 112 * MB);   // 112..118 (early)
    u16*  WsoutT= (u16*)(w8 + 112 * MB);   // 112..116 (after WqkvT dead)
    u16*  WoT   = (u16*)(w8 + 118 * MB);   // 118..120
    u16*  WsinT = (u16*)(w8 + 120 * MB);   // 120..128
    u16*  W1T   = (u16*)(w8 + 128 * MB);   // 128..136 (contiguous after WsinT!)

    dim3 blk(256);

    // --- build fused QKV weight (3072 x 1024 bf16, Bt layout) ---
    conv_t<<<dim3(32, 32), blk, 0, stream>>>(Wq, WqkvT, 1024, 1024, 0, 0, 0);
    convert_bf16<<<dim3(D_ * DC_ / 4 / 256), blk, 0, stream>>>(Wk_c, WkcB, D_ * DC_ / 4);
    convert_bf16<<<dim3(D_ * DC_ / 4 / 256), blk, 0, stream>>>(Wv_c, WvcB, D_ * DC_ / 4);
    conv_t<<<dim3(32, 8), blk, 0, stream>>>(Wk, WkTs, 256, 1024, 0, 0, 0);
    conv_t<<<dim3(32, 8), blk, 0, stream>>>(Wv, WvTs, 256, 1024, 0, 0, 0);
    gemm_bf16<2><<<dim3(8, 8), blk, 0, stream>>>(WkcB, WkTs, WqkvT + 1024 * 1024, 1024, 256, 1024);
    gemm_bf16<2><<<dim3(8, 8), blk, 0, stream>>>(WvcB, WvTs, WqkvT + 2048 * 1024, 1024, 256, 1024);

    convert_bf16<<<dim3(S_ * D_ / 4 / 256), blk, 0, stream>>>(src, srcb, S_ * D_ / 4);

    // Fused QKV projection: (S,1024) @ (1024,3072) -> qkv (S,3072)
    gemm_bf16<1><<<dim3(24, 32), blk, 0, stream>>>(srcb, WqkvT, qkv, QKVW_, 1024, QKVW_);

    // other weight conversions (WqkvT dead; WsoutT overlays it)
    conv_t<<<dim3(32, 32), blk, 0, stream>>>(Wo, WoT, 1024, 1024, 0, 0, 0);
    conv_t<<<dim3(128, 32), blk, 0, stream>>>(Wsin, WsinT, 1024, 4096, 0, 0, 1);
    conv_t<<<dim3(32, 64), blk, 0, stream>>>(Wsout, WsoutT, 2048, 1024, 0, 0, 0);
    conv_t<<<dim3(128, 32), blk, 0, stream>>>(W1, W1T, 1024, 4096, 0, 0, 1);

    // RoPE (table + vectorized apply)
    rope_table<<<dim3(T_ * 32 / 256), blk, 0, stream>>>(rtab);
    rope_apply<<<dim3(S_ * 2048 / 8 / 256), blk, 0, stream>>>(qkv, rtab);

    vt_conv<<<dim3(T_ / 32, 2, B_ * H_), blk, 0, stream>>>(qkv, vtg);
    attn_kernel<<<dim3(T_ / 64, B_ * H_), blk, 0, stream>>>(qkv, vtg, sab);

    // Wo projection, split-K=2 atomic into zeroed oproj
    hipMemsetAsync(oproj, 0, (size_t)S_ * D_ * 4, stream);
    gemm_bf16<4><<<dim3(8, 32, 2), blk, 0, stream>>>(sab, WoT, oproj, 1024, 1024, 1024);
    rmsnorm_res<1><<<dim3(S_), blk, 0, stream>>>(src, oproj, n1w, x1, x1b);

    // Merged FFN-in (shared + routed W1) with fused swiglu -> hbuf, hbuf2
    gemm_bf16<3><<<dim3(64, 32), blk, 0, stream>>>(x1b, WsinT, hbuf, 8192, 1024, 2048);

    // Shared FFN-out, split-K=2 atomic into zeroed ffn
    hipMemsetAsync(ffn, 0, (size_t)S_ * D_ * 4, stream);
    gemm_bf16<4><<<dim3(8, 32, 2), blk, 0, stream>>>(hbuf, WsoutT, ffn, 1024, 2048, 1024);

    // Gating (arrays in dead sab region)
    zero_counts<<<dim3(1), dim3(64), 0, stream>>>(counts);
    gate_kernel<<<dim3(S_ / 4), blk, 0, stream>>>(x1, Wg, We, gb, eb, toke, tokw, counts);
    scan_kernel<<<dim3(1), dim3(1), 0, stream>>>(counts, bases, cursors);
    scatter_kernel<<<dim3(S_ / 256), blk, 0, stream>>>(toke, tokw, cursors, list, wlist);

    // Routed experts
    conv_t<<<dim3(32, 64, 8), blk, 0, stream>>>(W2, w2t, 2048, 1024,
                                                (long)HID_ * D_, (long)D_ * HID_, 0);
    routed_gemm<<<dim3(8, E_ * 32), blk, 0, stream>>>(hbuf2, w2t, list, wlist,
                                                      bases, counts, ffn);

    rmsnorm_res<0><<<dim3(S_), blk, 0, stream>>>(x1, ffn, n2w, out, (u16*)nullptr);
}

// Round 7
// 670.066 us; speedup vs baseline: 6.5205x; 1.2084x over previous
//
#include <hip/hip_runtime.h>
#include <math.h>

#define D_    1024
#define H_    16
#define DH_   64
#define DC_   256
#define HID_  2048
#define E_    8
#define B_    2
#define T_    2048
#define S_    4096
#define EPS_  1e-6f
#define QKVW_ 3072   // fused qkv row width

typedef unsigned short u16;
typedef short bf16x8 __attribute__((ext_vector_type(8)));
typedef float f32x4 __attribute__((ext_vector_type(4)));

__device__ __forceinline__ float b2f(u16 u) {
    return __uint_as_float(((unsigned int)u) << 16);
}
__device__ __forceinline__ u16 f2b(float f) {
    unsigned int u = __float_as_uint(f);
    u += 0x7FFF + ((u >> 16) & 1);
    return (u16)(u >> 16);
}
__device__ __forceinline__ void g2l16(const u16* g, u16* l) {
    __builtin_amdgcn_global_load_lds(
        (const __attribute__((address_space(1))) void*)g,
        (__attribute__((address_space(3))) void*)l, 16, 0, 0);
}

// ---------------------------------------------------------------------------
// Transpose + fp32->bf16: in (K,N) fp32 -> out (N,K) bf16.
// perm=1: swiglu column interleave for fused epilogue.
// ---------------------------------------------------------------------------
__global__ __launch_bounds__(256) void conv_t(const float* __restrict__ in,
                                              u16* __restrict__ out,
                                              int K, int N,
                                              long inZ, long outZ, int perm) {
    in  += (long)blockIdx.z * inZ;
    out += (long)blockIdx.z * outZ;
    __shared__ float t[32][33];
    const int n0 = blockIdx.x * 32, k0 = blockIdx.y * 32;
    int src_n0 = n0;
    if (perm) {
        int t64 = n0 >> 6;
        src_n0 = ((n0 & 63) == 0) ? t64 * 32 : (N / 2 + t64 * 32);
    }
    const int tx = threadIdx.x & 31, ty = threadIdx.x >> 5;
#pragma unroll
    for (int i = 0; i < 4; i++)
        t[ty + 8 * i][tx] = in[(long)(k0 + ty + 8 * i) * N + src_n0 + tx];
    __syncthreads();
#pragma unroll
    for (int i = 0; i < 4; i++)
        out[(long)(n0 + ty + 8 * i) * K + k0 + tx] = f2b(t[tx][ty + 8 * i]);
}

// bf16 transpose V rows of fused qkv (stride QKVW_) per-head -> Vt [bh][64][T]
__global__ __launch_bounds__(256) void vt_conv(const u16* __restrict__ qkv,
                                               u16* __restrict__ vt) {
    __shared__ u16 t[32][34];
    const int bh = blockIdx.z;
    const int b = bh >> 4, h = bh & 15;
    const int t0 = blockIdx.x * 32, d0 = blockIdx.y * 32;
    const int tx = threadIdx.x & 31, ty = threadIdx.x >> 5;
#pragma unroll
    for (int i = 0; i < 4; i++)
        t[ty + 8 * i][tx] =
            qkv[((long)b * T_ + t0 + ty + 8 * i) * QKVW_ + 2048 + h * 64 + d0 + tx];
    __syncthreads();
#pragma unroll
    for (int i = 0; i < 4; i++)
        vt[((long)bh * 64 + d0 + ty + 8 * i) * T_ + t0 + tx] = t[tx][ty + 8 * i];
}

// Elementwise fp32 -> bf16
__global__ __launch_bounds__(256) void convert_bf16(const float* __restrict__ in,
                                                    u16* __restrict__ out, int n4) {
    int i = blockIdx.x * 256 + threadIdx.x;
    if (i >= n4) return;
    float4 f = ((const float4*)in)[i];
    ushort4 o;
    o.x = f2b(f.x); o.y = f2b(f.y); o.z = f2b(f.z); o.w = f2b(f.w);
    ((ushort4*)out)[i] = o;
}

// ---------------------------------------------------------------------------
// bf16 MFMA GEMM: C(M,N) = A(M,K) @ Bt(N,K)^T. 128x128, BK=32, 4 waves.
// OUTMODE 1: bf16 store | 2: bf16 transposed store (ldo=M)
// OUTMODE 3: swiglu epilogue, dual output: blockIdx.x>=32 -> Cp + S_*HID_
// OUTMODE 5: split-K (gridDim.z=2), fp32 plain store; z=0 -> Cp, z=1 -> Cp2
// ---------------------------------------------------------------------------
template<int OUTMODE>
__global__ __launch_bounds__(256) void gemm_bf16(const u16* __restrict__ A,
                                                 const u16* __restrict__ Bt,
                                                 void* __restrict__ Cp,
                                                 int N, int K, int ldo,
                                                 void* __restrict__ Cp2) {
    __shared__ u16 As[128 * 32];
    __shared__ u16 Bs[128 * 32];
    const int tid  = threadIdx.x;
    const int lane = tid & 63;
    const int wv   = tid >> 6;
    const int wm   = wv >> 1, wn = wv & 1;
    const long row0 = (long)blockIdx.y * 128;
    const long col0 = (long)blockIdx.x * 128;
    const int Klocal = K / gridDim.z;
    const long koff  = (long)blockIdx.z * Klocal;

    f32x4 acc[4][4];
#pragma unroll
    for (int i = 0; i < 4; i++)
#pragma unroll
        for (int j = 0; j < 4; j++) acc[i][j] = (f32x4){0.f, 0.f, 0.f, 0.f};

    const int sr = tid >> 2;
    const int sc = (tid & 3) << 3;
    const u16* Ag  = A  + (row0 + sr) * (long)K + koff + sc;
    const u16* Ag2 = Ag + 64 * (long)K;
    const u16* Bg  = Bt + (col0 + sr) * (long)K + koff + sc;
    const u16* Bg2 = Bg + 64 * (long)K;
    u16* lA  = As + tid * 8;
    u16* lA2 = As + 2048 + tid * 8;
    u16* lB  = Bs + tid * 8;
    u16* lB2 = Bs + 2048 + tid * 8;

    const int fl = lane & 15;
    const int fk = (lane >> 4) << 3;
    const u16* ArA = As + (wm * 64 + fl) * 32 + fk;
    const u16* BrB = Bs + (wn * 64 + fl) * 32 + fk;

    for (int k0 = 0; k0 < Klocal; k0 += 32) {
        __syncthreads();
        g2l16(Ag + k0, lA);
        g2l16(Ag2 + k0, lA2);
        g2l16(Bg + k0, lB);
        g2l16(Bg2 + k0, lB2);
        __syncthreads();
        bf16x8 af[4], bfr[4];
#pragma unroll
        for (int mi = 0; mi < 4; mi++) af[mi]  = *(const bf16x8*)(ArA + mi * 512);
#pragma unroll
        for (int ni = 0; ni < 4; ni++) bfr[ni] = *(const bf16x8*)(BrB + ni * 512);
#pragma unroll
        for (int mi = 0; mi < 4; mi++)
#pragma unroll
            for (int ni = 0; ni < 4; ni++)
                acc[mi][ni] = __builtin_amdgcn_mfma_f32_16x16x32_bf16(
                    af[mi], bfr[ni], acc[mi][ni], 0, 0, 0);
    }

    const int cr = (lane >> 4) << 2;
    const int cc = lane & 15;
#pragma unroll
    for (int mi = 0; mi < 4; mi++) {
#pragma unroll
        for (int r = 0; r < 4; r++) {
            long grow = row0 + wm * 64 + mi * 16 + cr + r;
            if (OUTMODE == 3) {
                u16* outb = (u16*)Cp + (long)(blockIdx.x >> 5) * S_ * HID_;
                u16* hrow = outb + grow * ldo + (blockIdx.x & 31) * 64 + wn * 32;
#pragma unroll
                for (int ni = 0; ni < 2; ni++) {
                    float a = acc[mi][ni][r], b = acc[mi][ni + 2][r];
                    float sig = 1.f / (1.f + __expf(-a));
                    hrow[ni * 16 + cc] = f2b(a * sig * b);
                }
            } else {
#pragma unroll
                for (int ni = 0; ni < 4; ni++) {
                    long gcol = col0 + wn * 64 + ni * 16 + cc;
                    float v = acc[mi][ni][r];
                    if (OUTMODE == 1)      ((u16*)Cp)[grow * ldo + gcol] = f2b(v);
                    else if (OUTMODE == 2) ((u16*)Cp)[gcol * ldo + grow] = f2b(v);
                    else {
                        float* basep = (float*)(blockIdx.z ? Cp2 : Cp);
                        basep[grow * ldo + gcol] = v;
                    }
                }
            }
        }
    }
}

// ---------------------------------------------------------------------------
// Routed-expert bf16 MFMA GEMM (gathered rows, scaled atomicAdd epilogue)
// ---------------------------------------------------------------------------
__global__ __launch_bounds__(256) void routed_gemm(const u16* __restrict__ Hh,
                                                   const u16* __restrict__ W2T,
                                                   const int* __restrict__ list,
                                                   const float* __restrict__ wlist,
                                                   const int* __restrict__ bases,
                                                   const int* __restrict__ counts,
                                                   float* __restrict__ Cout) {
    const int e    = blockIdx.y >> 5;
    const int tile = blockIdx.y & 31;
    const int cnt  = counts[e];
    if (tile * 128 >= cnt) return;
    const int base = bases[e];

    __shared__ u16 As[128 * 32];
    __shared__ u16 Bs[128 * 32];
    __shared__ int   toks[128];
    __shared__ float wrow[128];

    const int tid = threadIdx.x;
    if (tid < 128) {
        int ridx = tile * 128 + tid;
        if (ridx < cnt) { toks[tid] = list[base + ridx]; wrow[tid] = wlist[base + ridx]; }
        else            { toks[tid] = -1;                wrow[tid] = 0.f; }
    }
    __syncthreads();

    const int lane = tid & 63;
    const int wv   = tid >> 6;
    const int wm   = wv >> 1, wn = wv & 1;
    const long col0 = (long)blockIdx.x * 128;

    f32x4 acc[4][4];
#pragma unroll
    for (int i = 0; i < 4; i++)
#pragma unroll
        for (int j = 0; j < 4; j++) acc[i][j] = (f32x4){0.f, 0.f, 0.f, 0.f};

    const int sr = tid >> 2;
    const int sc = (tid & 3) << 3;
    const int t1 = toks[sr], t2 = toks[sr + 64];
    const u16* Ag  = Hh + (long)(t1 < 0 ? 0 : t1) * HID_ + sc;
    const u16* Ag2 = Hh + (long)(t2 < 0 ? 0 : t2) * HID_ + sc;
    const u16* Bg  = W2T + (long)e * D_ * HID_ + (col0 + sr) * (long)HID_ + sc;
    const u16* Bg2 = Bg + 64 * (long)HID_;
    u16* lA  = As + tid * 8;
    u16* lA2 = As + 2048 + tid * 8;
    u16* lB  = Bs + tid * 8;
    u16* lB2 = Bs + 2048 + tid * 8;

    const int fl = lane & 15;
    const int fk = (lane >> 4) << 3;
    const u16* ArA = As + (wm * 64 + fl) * 32 + fk;
    const u16* BrB = Bs + (wn * 64 + fl) * 32 + fk;

    for (int k0 = 0; k0 < HID_; k0 += 32) {
        __syncthreads();
        g2l16(Ag + k0, lA);
        g2l16(Ag2 + k0, lA2);
        g2l16(Bg + k0, lB);
        g2l16(Bg2 + k0, lB2);
        __syncthreads();
        bf16x8 af[4], bfr[4];
#pragma unroll
        for (int mi = 0; mi < 4; mi++) af[mi]  = *(const bf16x8*)(ArA + mi * 512);
#pragma unroll
        for (int ni = 0; ni < 4; ni++) bfr[ni] = *(const bf16x8*)(BrB + ni * 512);
#pragma unroll
        for (int mi = 0; mi < 4; mi++)
#pragma unroll
            for (int ni = 0; ni < 4; ni++)
                acc[mi][ni] = __builtin_amdgcn_mfma_f32_16x16x32_bf16(
                    af[mi], bfr[ni], acc[mi][ni], 0, 0, 0);
    }

    const int cr = (lane >> 4) << 2;
    const int cc = lane & 15;
#pragma unroll
    for (int mi = 0; mi < 4; mi++) {
#pragma unroll
        for (int r = 0; r < 4; r++) {
            int rr = wm * 64 + mi * 16 + cr + r;
            int tk = toks[rr];
            if (tk < 0) continue;
            float wvw = wrow[rr];
            float* crow = Cout + (long)tk * D_ + col0 + wn * 64;
#pragma unroll
            for (int ni = 0; ni < 4; ni++)
                atomicAdd(crow + ni * 16 + cc, acc[mi][ni][r] * wvw);
        }
    }
}

// ---------------------------------------------------------------------------
// RoPE: sincos table (T_ x 32) then vectorized apply on q,k cols of qkv.
// ---------------------------------------------------------------------------
__global__ __launch_bounds__(256) void rope_table(float2* __restrict__ tab) {
    int idx = blockIdx.x * 256 + threadIdx.x;     // 65536
    int t = idx >> 5, i = idx & 31;
    float ang = (float)t * powf(10000.f, -(float)i / 32.f);
    float sn, cs;
    sincosf(ang, &sn, &cs);
    tab[idx] = make_float2(sn, cs);
}

__global__ __launch_bounds__(256) void rope_apply(u16* __restrict__ qkv,
                                                  const float2* __restrict__ tab) {
    long p = (long)blockIdx.x * 256 + threadIdx.x;   // S_*2048/8 groups
    int s  = (int)(p >> 8);
    int c8 = (int)(p & 255) << 3;
    int t  = s & (T_ - 1);
    const float2* tp = tab + t * 32 + ((c8 & 63) >> 1);
    u16* px = qkv + (long)s * QKVW_ + c8;
    bf16x8 v = *(const bf16x8*)px;
    bf16x8 o;
#pragma unroll
    for (int j = 0; j < 4; j++) {
        float x1 = b2f((u16)v[2 * j]), x2 = b2f((u16)v[2 * j + 1]);
        float2 sc = tp[j];
        o[2 * j]     = (short)f2b(x1 * sc.y - x2 * sc.x);
        o[2 * j + 1] = (short)f2b(x1 * sc.x + x2 * sc.y);
    }
    *(bf16x8*)px = o;
}

// ---------------------------------------------------------------------------
// MFMA flash attention, 128-key x 128-query tiles. grid (T/128, B*H),
// 512 thr = 8 waves x 16 q-rows. LDS: Ks 128x64, Vs 64x128, Ps 8x16x128 = 64KB.
// 2 blocks/CU, grid 512 = exactly 2/CU -> no tail.
// ---------------------------------------------------------------------------
__global__ __launch_bounds__(512) void attn_kernel(const u16* __restrict__ qkv,
                                                   const u16* __restrict__ vtg,
                                                   u16* __restrict__ sab) {
    __shared__ u16 Ks[128 * 64];
    __shared__ u16 Vs[64 * 128];
    __shared__ u16 Ps[8][16 * 128];
    const int tid  = threadIdx.x;
    const int lane = tid & 63;
    const int w    = tid >> 6;          // 0..7
    const int bh = blockIdx.y;
    const int b  = bh >> 4, h = bh & 15;
    const long tok0 = (long)b * T_ + blockIdx.x * 128;
    const int fl = lane & 15;
    const int fq = lane >> 4;

    bf16x8 qf0, qf1;
    {
        const u16* qp = qkv + (tok0 + w * 16 + fl) * QKVW_ + h * 64 + fq * 8;
        qf0 = *(const bf16x8*)qp;
        qf1 = *(const bf16x8*)(qp + 32);
    }

    const u16* kb0 = qkv + ((long)b * T_) * QKVW_ + 1024 + h * 64;
    const u16* vb0 = vtg + ((long)bh * 64) * T_;

    float m_[4], l_[4];
    f32x4 oacc[4];
#pragma unroll
    for (int i = 0; i < 4; i++) {
        m_[i] = -1e30f; l_[i] = 0.f;
        oacc[i] = (f32x4){0.f, 0.f, 0.f, 0.f};
    }

    for (int kt = 0; kt < T_ / 128; kt++) {
        __syncthreads();
        // K: 1024 slots (row=i>>3 of 128 keys, grp=i&7), 2 passes of 512
#pragma unroll
        for (int ps = 0; ps < 2; ps++) {
            int i = tid + ps * 512;
            int row = i >> 3, gg = i & 7;
            g2l16(kb0 + (long)(kt * 128 + row) * QKVW_ + ((gg ^ (row & 7)) << 3),
                  Ks + i * 8);
        }
        // V: 1024 slots (row=i>>4 of 64 d, grp=i&15), 2 passes of 512
#pragma unroll
        for (int ps = 0; ps < 2; ps++) {
            int i = tid + ps * 512;
            int row = i >> 4, gg = i & 15;
            g2l16(vb0 + (long)row * T_ + kt * 128 + ((gg ^ (row & 15)) << 3),
                  Vs + i * 8);
        }
        __syncthreads();

        // S = Q K^T  (16 q-rows x 128 k-cols per wave)
        f32x4 sacc[8];
#pragma unroll
        for (int ni = 0; ni < 8; ni++) sacc[ni] = (f32x4){0.f, 0.f, 0.f, 0.f};
#pragma unroll
        for (int ks = 0; ks < 2; ks++) {
            bf16x8 qq = ks ? qf1 : qf0;
#pragma unroll
            for (int ni = 0; ni < 8; ni++) {
                bf16x8 kf = *(const bf16x8*)(Ks + (ni * 16 + fl) * 64 +
                                             (((ks * 4 + fq) ^ (fl & 7)) << 3));
                sacc[ni] = __builtin_amdgcn_mfma_f32_16x16x32_bf16(qq, kf, sacc[ni], 0, 0, 0);
            }
        }

        float rmax[4];
#pragma unroll
        for (int r = 0; r < 4; r++) {
            float mm = sacc[0][r];
#pragma unroll
            for (int ni = 1; ni < 8; ni++) mm = fmaxf(mm, sacc[ni][r]);
            rmax[r] = mm * 0.125f;
        }
#pragma unroll
        for (int off = 1; off < 16; off <<= 1)
#pragma unroll
            for (int r = 0; r < 4; r++) rmax[r] = fmaxf(rmax[r], __shfl_xor(rmax[r], off));
        float alpha[4], psum[4];
#pragma unroll
        for (int r = 0; r < 4; r++) {
            float nm = fmaxf(m_[r], rmax[r]);
            alpha[r] = __expf(m_[r] - nm);
            m_[r] = nm;
            psum[r] = 0.f;
        }
        u16* pst = Ps[w];
#pragma unroll
        for (int ni = 0; ni < 8; ni++) {
            int colg = ni * 2 + (fl >> 3);
            int cl   = fl & 7;
#pragma unroll
            for (int r = 0; r < 4; r++) {
                int row = fq * 4 + r;
                float p = __expf(sacc[ni][r] * 0.125f - m_[r]);
                psum[r] += p;
                pst[row * 128 + ((colg ^ (row & 15)) << 3) + cl] = f2b(p);
            }
        }
#pragma unroll
        for (int off = 1; off < 16; off <<= 1)
#pragma unroll
            for (int r = 0; r < 4; r++) psum[r] += __shfl_xor(psum[r], off);
#pragma unroll
        for (int r = 0; r < 4; r++) l_[r] = l_[r] * alpha[r] + psum[r];
#pragma unroll
        for (int ni = 0; ni < 4; ni++)
#pragma unroll
            for (int r = 0; r < 4; r++) oacc[ni][r] *= alpha[r];

        // O += P V   (K=128 over 4 ks steps)
#pragma unroll
        for (int ks = 0; ks < 4; ks++) {
            bf16x8 pf = *(const bf16x8*)(pst + fl * 128 +
                                         (((ks * 4 + fq) ^ fl) << 3));
#pragma unroll
            for (int ni = 0; ni < 4; ni++) {
                bf16x8 vf = *(const bf16x8*)(Vs + (ni * 16 + fl) * 128 +
                                             (((ks * 4 + fq) ^ fl) << 3));
                oacc[ni] = __builtin_amdgcn_mfma_f32_16x16x32_bf16(pf, vf, oacc[ni], 0, 0, 0);
            }
        }
    }

#pragma unroll
    for (int r = 0; r < 4; r++) {
        float inv = 1.f / l_[r];
        u16* op = sab + (tok0 + w * 16 + fq * 4 + r) * D_ + h * 64 + fl;
#pragma unroll
        for (int ni = 0; ni < 4; ni++) op[ni * 16] = f2b(oacc[ni][r] * inv);
    }
}

// ---------------------------------------------------------------------------
// Residual add (3 inputs) + RMSNorm. BF=1 additionally writes bf16 copy.
// ---------------------------------------------------------------------------
template<int BF>
__global__ __launch_bounds__(256) void rmsnorm_res(const float* __restrict__ a,
                                                   const float* __restrict__ b,
                                                   const float* __restrict__ b2,
                                                   const float* __restrict__ w,
                                                   float* __restrict__ outf,
                                                   u16* __restrict__ outb) {
    const int s = blockIdx.x;
    const float* ar = a + (long)s * D_;
    const float* br = b + (long)s * D_;
    const float* cr2 = b2 + (long)s * D_;
    float y[4];
    float ss = 0.f;
#pragma unroll
    for (int kx = 0; kx < 4; kx++) {
        int j = threadIdx.x + kx * 256;
        y[kx] = ar[j] + br[j] + cr2[j];
        ss += y[kx] * y[kx];
    }
    __shared__ float red[4];
#pragma unroll
    for (int off = 32; off > 0; off >>= 1) ss += __shfl_down(ss, off);
    int lane = threadIdx.x & 63, wv = threadIdx.x >> 6;
    if (lane == 0) red[wv] = ss;
    __syncthreads();
    float tot = red[0] + red[1] + red[2] + red[3];
    float scl = rsqrtf(tot / (float)D_ + EPS_);
    float* orow = outf + (long)s * D_;
#pragma unroll
    for (int kx = 0; kx < 4; kx++) {
        int j = threadIdx.x + kx * 256;
        float v = y[kx] * scl * w[j];
        orow[j] = v;
        if (BF) outb[(long)s * D_ + j] = f2b(v);
    }
}

// ---------------------------------------------------------------------------
// Gating (fp32): one wave per token. Writes per-token top-2 (expert, weight).
// ---------------------------------------------------------------------------
__global__ __launch_bounds__(256) void gate_kernel(const float* __restrict__ x,
                                                   const float* __restrict__ Wg,
                                                   const float* __restrict__ We,
                                                   const float* __restrict__ gb,
                                                   const float* __restrict__ eb,
                                                   int* __restrict__ tok_e,
                                                   float* __restrict__ tok_w) {
    const int wave = threadIdx.x >> 6;
    const int lane = threadIdx.x & 63;
    const int s = blockIdx.x * 4 + wave;
    const float* xr = x + (long)s * D_;
    float g0 = 0.f, g1 = 0.f;
    float ee[8];
#pragma unroll
    for (int e = 0; e < 8; e++) ee[e] = 0.f;
    for (int j = lane; j < D_; j += 64) {
        float xv = xr[j];
        g0 += xv * Wg[j * 2 + 0];
        g1 += xv * Wg[j * 2 + 1];
#pragma unroll
        for (int e = 0; e < 8; e++) ee[e] += xv * We[j * 8 + e];
    }
#pragma unroll
    for (int off = 32; off > 0; off >>= 1) {
        g0 += __shfl_down(g0, off);
        g1 += __shfl_down(g1, off);
#pragma unroll
        for (int e = 0; e < 8; e++) ee[e] += __shfl_down(ee[e], off);
    }
    if (lane == 0) {
        g0 += gb[0];
        g1 += gb[1];
        int gidx = (g1 > g0) ? 1 : 0;
        float gm = fmaxf(g0, g1);
        float p0 = expf(g0 - gm), p1 = expf(g1 - gm);
        float gprob = (gidx ? p1 : p0) / (p0 + p1);
        int base = gidx * 4;
        float pe[4];
        float em = -1e30f;
#pragma unroll
        for (int i = 0; i < 4; i++) {
            pe[i] = ee[base + i] + eb[base + i];
            em = fmaxf(em, pe[i]);
        }
        float sum = 0.f;
#pragma unroll
        for (int i = 0; i < 4; i++) { pe[i] = expf(pe[i] - em); sum += pe[i]; }
        float inv = gprob / sum;
#pragma unroll
        for (int i = 0; i < 4; i++) pe[i] *= inv;
        int i1 = 0;
        for (int i = 1; i < 4; i++) if (pe[i] > pe[i1]) i1 = i;
        int i2 = -1;
        for (int i = 0; i < 4; i++) {
            if (i == i1) continue;
            if (i2 < 0 || pe[i] > pe[i2]) i2 = i;
        }
        tok_e[s * 2 + 0] = base + i1;
        tok_e[s * 2 + 1] = base + i2;
        tok_w[s * 2 + 0] = pe[i1];
        tok_w[s * 2 + 1] = pe[i2];
    }
}

// ---------------------------------------------------------------------------
// Single-block routing build: histogram + scan + scatter in LDS.
// ---------------------------------------------------------------------------
__global__ __launch_bounds__(256) void route_build(const int* __restrict__ tok_e,
                                                   const float* __restrict__ tok_w,
                                                   int* __restrict__ counts_g,
                                                   int* __restrict__ bases_g,
                                                   int* __restrict__ list,
                                                   float* __restrict__ wlist) {
    __shared__ int cnt[E_], bas[E_], cur[E_];
    const int tid = threadIdx.x;
    if (tid < E_) cnt[tid] = 0;
    __syncthreads();
    for (int i = tid; i < 2 * S_; i += 256) atomicAdd(&cnt[tok_e[i]], 1);
    __syncthreads();
    if (tid == 0) {
        int acc = 0;
        for (int e = 0; e < E_; e++) { bas[e] = acc; cur[e] = acc; acc += cnt[e]; }
    }
    __syncthreads();
    if (tid < E_) { counts_g[tid] = cnt[tid]; bases_g[tid] = bas[tid]; }
    for (int i = tid; i < 2 * S_; i += 256) {
        int e = tok_e[i];
        int p = atomicAdd(&cur[e], 1);
        list[p] = i >> 1;
        wlist[p] = tok_w[i];
    }
}

// ---------------------------------------------------------------------------
extern "C" void kernel_launch(void* const* d_in, const int* in_sizes, int n_in,
                              void* d_out, int out_size, void* d_ws, size_t ws_size,
                              hipStream_t stream) {
    const float* src  = (const float*)d_in[0];
    const float* Wq   = (const float*)d_in[1];
    const float* Wk_c = (const float*)d_in[2];
    const float* Wv_c = (const float*)d_in[3];
    const float* Wk   = (const float*)d_in[4];
    const float* Wv   = (const float*)d_in[5];
    const float* Wo   = (const float*)d_in[6];
    const float* Wsin = (const float*)d_in[7];
    const float* Wsout= (const float*)d_in[8];
    const float* W1   = (const float*)d_in[9];
    const float* W2   = (const float*)d_in[10];
    const float* Wg   = (const float*)d_in[11];
    const float* We   = (const float*)d_in[12];
    const float* gb   = (const float*)d_in[13];
    const float* eb   = (const float*)d_in[14];
    const float* n1w  = (const float*)d_in[15];
    const float* n2w  = (const float*)d_in[16];
    float* out = (float*)d_out;

    const size_t MB = 1u << 20;
    char* w8 = (char*)d_ws;
    // Layout (MiB offsets). Lifetimes:
    u16*  qkv   = (u16*)(w8);              // 0..24; dead after attn
    u16*  vtg   = (u16*)(w8 + 24 * MB);    // 24..32; dead after attn
    float* oproj0 = (float*)(w8);          // 0..16 (after attn; dead after rmsnorm1)
    float* oproj1 = (float*)(w8 + 16 * MB);// 16..32 (same)
    u16*  w2t   = (u16*)(w8);              // 0..32 (after rmsnorm1)
    u16*  WkcB  = (u16*)(w8 + 24 * MB);    // early temps (dead before vt_conv)
    u16*  WvcB  = (u16*)(w8 + 24 * MB + 512 * 1024);
    u16*  WkTs  = (u16*)(w8 + 25 * MB);
    u16*  WvTs  = (u16*)(w8 + 25 * MB + 512 * 1024);
    u16*  sab   = (u16*)(w8 + 32 * MB);    // 32..40; dead after Wo gemm
    float* tokw = (float*)(w8 + 32 * MB);  // gating arrays overlay dead sab
    float* wlist = tokw + 2 * S_;
    int* toke   = (int*)(wlist + 2 * S_);
    int* list   = toke + 2 * S_;
    int* counts = list + 2 * S_;
    int* bases  = counts + E_;
    float* x1   = (float*)(w8 + 40 * MB);  // 40..56
    float* ffn0 = (float*)(w8 + 56 * MB);  // 56..72
    u16*  x1b   = (u16*)(w8 + 72 * MB);    // 72..80 (dead after FFN-in gemm)
    u16*  hbuf  = (u16*)(w8 + 80 * MB);    // 80..96 (shared-FFN h)
    u16*  srcb  = (u16*)(w8 + 96 * MB);    // 96..104 (early; dead after QKV gemm)
    float2* rtab= (float2*)(w8 + 104 * MB);// 104..104.5 (dead after rope_apply)
    u16*  hbuf2 = (u16*)(w8 + 96 * MB);    // 96..112 (routed h; after srcb/rtab dead)
    u16*  WqkvT = (u16*)(w8 + 112 * MB);   // 112..118 (early)
    u16*  WsoutT= (u16*)(w8 + 112 * MB);   // 112..116 (after WqkvT dead)
    u16*  WoT   = (u16*)(w8 + 118 * MB);   // 118..120
    u16*  WsinT = (u16*)(w8 + 120 * MB);   // 120..128 (dead after FFN-in)
    u16*  W1T   = (u16*)(w8 + 128 * MB);   // 128..136 (dead after FFN-in)
    float* ffn1 = (float*)(w8 + 120 * MB); // 120..136 (overlays WsinT/W1T, late)

    dim3 blk(256);

    // --- build fused QKV weight (3072 x 1024 bf16, Bt layout) ---
    conv_t<<<dim3(32, 32), blk, 0, stream>>>(Wq, WqkvT, 1024, 1024, 0, 0, 0);
    convert_bf16<<<dim3(D_ * DC_ / 4 / 256), blk, 0, stream>>>(Wk_c, WkcB, D_ * DC_ / 4);
    convert_bf16<<<dim3(D_ * DC_ / 4 / 256), blk, 0, stream>>>(Wv_c, WvcB, D_ * DC_ / 4);
    conv_t<<<dim3(32, 8), blk, 0, stream>>>(Wk, WkTs, 256, 1024, 0, 0, 0);
    conv_t<<<dim3(32, 8), blk, 0, stream>>>(Wv, WvTs, 256, 1024, 0, 0, 0);
    gemm_bf16<2><<<dim3(8, 8), blk, 0, stream>>>(WkcB, WkTs, WqkvT + 1024 * 1024, 1024, 256, 1024, nullptr);
    gemm_bf16<2><<<dim3(8, 8), blk, 0, stream>>>(WvcB, WvTs, WqkvT + 2048 * 1024, 1024, 256, 1024, nullptr);

    convert_bf16<<<dim3(S_ * D_ / 4 / 256), blk, 0, stream>>>(src, srcb, S_ * D_ / 4);

    // Fused QKV projection: (S,1024) @ (1024,3072) -> qkv (S,3072)
    gemm_bf16<1><<<dim3(24, 32), blk, 0, stream>>>(srcb, WqkvT, qkv, QKVW_, 1024, QKVW_, nullptr);

    // other weight conversions (WqkvT dead; WsoutT overlays it)
    conv_t<<<dim3(32, 32), blk, 0, stream>>>(Wo, WoT, 1024, 1024, 0, 0, 0);
    conv_t<<<dim3(128, 32), blk, 0, stream>>>(Wsin, WsinT, 1024, 4096, 0, 0, 1);
    conv_t<<<dim3(32, 64), blk, 0, stream>>>(Wsout, WsoutT, 2048, 1024, 0, 0, 0);
    conv_t<<<dim3(128, 32), blk, 0, stream>>>(W1, W1T, 1024, 4096, 0, 0, 1);

    // RoPE (table + vectorized apply)
    rope_table<<<dim3(T_ * 32 / 256), blk, 0, stream>>>(rtab);
    rope_apply<<<dim3(S_ * 2048 / 8 / 256), blk, 0, stream>>>(qkv, rtab);

    vt_conv<<<dim3(T_ / 32, 2, B_ * H_), blk, 0, stream>>>(qkv, vtg);
    attn_kernel<<<dim3(T_ / 128, B_ * H_), dim3(512), 0, stream>>>(qkv, vtg, sab);

    // Wo projection, split-K=2 plain stores into two buffers
    gemm_bf16<5><<<dim3(8, 32, 2), blk, 0, stream>>>(sab, WoT, oproj0, 1024, 1024, 1024, oproj1);
    rmsnorm_res<1><<<dim3(S_), blk, 0, stream>>>(src, oproj0, oproj1, n1w, x1, x1b);

    // Merged FFN-in (shared + routed W1) with fused swiglu -> hbuf, hbuf2
    gemm_bf16<3><<<dim3(64, 32), blk, 0, stream>>>(x1b, WsinT, hbuf, 8192, 1024, 2048, nullptr);

    // Shared FFN-out, split-K=2 plain stores -> ffn0, ffn1
    gemm_bf16<5><<<dim3(8, 32, 2), blk, 0, stream>>>(hbuf, WsoutT, ffn0, 1024, 2048, 1024, ffn1);

    // Gating + routing lists
    gate_kernel<<<dim3(S_ / 4), blk, 0, stream>>>(x1, Wg, We, gb, eb, toke, tokw);
    route_build<<<dim3(1), blk, 0, stream>>>(toke, tokw, counts, bases, list, wlist);

    // Routed experts: W2 transpose, gathered GEMM atomicAdd onto ffn0
    conv_t<<<dim3(32, 64, 8), blk, 0, stream>>>(W2, w2t, 2048, 1024,
                                                (long)HID_ * D_, (long)D_ * HID_, 0);
    routed_gemm<<<dim3(8, E_ * 32), blk, 0, stream>>>(hbuf2, w2t, list, wlist,
                                                      bases, counts, ffn0);

    rmsnorm_res<0><<<dim3(S_), blk, 0, stream>>>(x1, ffn0, ffn1, n2w, out, (u16*)nullptr);
}